// Round 9
// baseline (6227.116 us; speedup 1.0000x reference)
//
#include <hip/hip_runtime.h>

#define TT 32
#define NB 16   // nodes per GRU block

typedef __attribute__((ext_vector_type(8))) short short8;
typedef __attribute__((ext_vector_type(4))) float f32x4;

// ---------- helpers ----------
__device__ __host__ inline unsigned short f2bf(float f) {
    unsigned u = __float_as_uint(f);
    return (unsigned short)((u + 0x7FFFu + ((u >> 16) & 1u)) >> 16);
}
__device__ inline float bf2f(unsigned short h) {
    return __uint_as_float(((unsigned)h) << 16);
}
__device__ inline unsigned fenc(float f) {
    unsigned b = __float_as_uint(f);
    return (b & 0x80000000u) ? ~b : (b | 0x80000000u);
}
__device__ inline float fdec(unsigned u) {
    unsigned b = (u & 0x80000000u) ? (u & 0x7FFFFFFFu) : ~u;
    return __uint_as_float(b);
}
#define ENC_NEG_INF 0x007FFFFFu   // fenc(-inf)

// ---------- weight prep ----------
__global__ void prep_w(const float* __restrict__ Wih_f, const float* __restrict__ Whh_f,
                       const float* __restrict__ Wih_b, const float* __restrict__ Whh_b,
                       const float* __restrict__ Wg,
                       unsigned short* __restrict__ Whi_f, unsigned short* __restrict__ Wlo_f,
                       unsigned short* __restrict__ Whi_b, unsigned short* __restrict__ Wlo_b,
                       float* __restrict__ Wgt) {
    int i = blockIdx.x * 256 + threadIdx.x;
    if (i < 384 * 256) {
        int col = i / 256, k = i % 256;
        float ff = (k < 128) ? Wih_f[col * 128 + k] : Whh_f[col * 128 + (k - 128)];
        float fb = (k < 128) ? Wih_b[col * 128 + k] : Whh_b[col * 128 + (k - 128)];
        unsigned short hf = f2bf(ff);
        Whi_f[i] = hf; Wlo_f[i] = f2bf(ff - bf2f(hf));
        unsigned short hb = f2bf(fb);
        Whi_b[i] = hb; Wlo_b[i] = f2bf(fb - bf2f(hb));
    }
    if (i < 256 * 256) {
        int k = i / 256, j = i % 256;
        Wgt[i] = Wg[j * 256 + k];
    }
}

// ---------- emb bf16 hi/lo plane prep (one-time; makes GRU staging a pure copy) ----
__global__ void prep_emb(const float* __restrict__ emb, unsigned short* __restrict__ ehi,
                         unsigned short* __restrict__ elo, int n) {
    int i = blockIdx.x * 256 + threadIdx.x;
    if (i < n) {
        float e = emb[i];
        unsigned short h = f2bf(e);
        ehi[i] = h; elo[i] = f2bf(e - bf2f(h));
    }
}

// ---------- fused biGRU: high-occupancy, B streamed from L2, dbuf LDS ----------
// 512 threads = 8 waves, 16 nodes/block. Wave w owns cols [16w,16w+16) of each
// gate (r,z,n). B-fragments stream from L2 each step (R4-R8 post-mortem: the
// compiler reloads them regardless of any residency coaxing, and the pipe math
// shows that's fine — L2 BW per CU is not the limit; LATENCY at low occupancy
// is). amdgpu_waves_per_eu(6): target <=85 VGPR -> 3 blocks/CU resident
// (6 waves/SIMD) for latency hiding. LDS 3x32KB = 96KB <= 160KB.
// A (LDS, x2 buffers): [16 node][256 k] bf16 hi+lo planes, XOR-swizzled
// (byte ^= (row&7)<<4). k<128 = x_t (pure-copy staged), k>=128 = h.
// fp32 h carry in 4 regs/lane. One barrier per step.
__global__ __launch_bounds__(512)
__attribute__((amdgpu_waves_per_eu(6)))
void gru_kernel(const int* __restrict__ X,
                const unsigned short* __restrict__ ehi, const unsigned short* __restrict__ elo,
                const unsigned short* __restrict__ Whi_f, const unsigned short* __restrict__ Wlo_f,
                const unsigned short* __restrict__ Whi_b, const unsigned short* __restrict__ Wlo_b,
                const float* __restrict__ bih_f, const float* __restrict__ bhh_f,
                const float* __restrict__ bih_b, const float* __restrict__ bhh_b,
                float* __restrict__ q_out, float* __restrict__ qn_out, int N) {
    const int dir  = blockIdx.y;
    const int base = blockIdx.x * NB;
    const int tid  = threadIdx.x;
    const int lane = tid & 63;
    const int w    = tid >> 6;      // wave 0..7
    const int l15  = lane & 15;
    const int l4   = lane >> 4;     // 0..3

    const unsigned short* __restrict__ Whi = dir ? Whi_b : Whi_f;
    const unsigned short* __restrict__ Wlo = dir ? Wlo_b : Wlo_f;
    const float* __restrict__ bih = dir ? bih_b : bih_f;
    const float* __restrict__ bhh = dir ? bhh_b : bhh_f;

    __shared__ __align__(16) char smem[32768];   // 2 buffers x (Ahi 8K + Alo 8K)

    const int j = w * 16 + l15;        // owned output col (per gate)
    const float bR  = bih[j]       + bhh[j];
    const float bZ  = bih[j + 128] + bhh[j + 128];
    const float bXN = bih[j + 256];
    const float bHN = bhh[j + 256];

    // B-fragment base offsets (ushort index); kc adds kc*32
    const int bbase = j * 256 + l4 * 8;

    // A-frag read base: row = l15, kbyte = kc*64 + l4*16
    const int amask = (l15 & 7) << 4;
    const int abase = l15 * 512 + l4 * 16;

    // zero h-region of buffer 0 (rows 0..15, bytes 256..511, both planes)
    for (int i = tid; i < 2048; i += 512) {
        int plane = i >> 10, idx = i & 1023;
        int row = idx >> 6, d = idx & 63;
        *(unsigned*)(smem + plane * 8192 + row * 512 + 256 + d * 4) = 0u;
    }

    // staging: thread -> (node snode, 4 k at sk); pure 8B+8B copy
    const int snode = tid >> 5;
    const int sk    = (tid & 31) * 4;
    const int sb    = (snode * 512 + sk * 2) ^ ((snode & 7) << 4);
    int node_s = base + snode; if (node_s >= N) node_s = N - 1;
    const int* Xrow = X + (size_t)node_s * TT;
    auto teff = [&](int t) { return dir ? (TT - 1 - t) : t; };

    { // stage x(0) into buffer 0
        int idx0 = Xrow[teff(0)];
        *(ushort4*)(smem + sb)        = *(const ushort4*)(ehi + (size_t)idx0 * 128 + sk);
        *(ushort4*)(smem + 8192 + sb) = *(const ushort4*)(elo + (size_t)idx0 * 128 + sk);
    }
    int idxA = Xrow[teff(1)];    // index for x(1), prefetched

    float hprev[4] = {0.f, 0.f, 0.f, 0.f};
    const int jd = j & ~1;       // even col of the (j, j^1) pair

    for (int t = 0; t < TT; t++) {
        __syncthreads();   // buf[cur] (x_t + h_t) fully written

        char* pA = smem + (t & 1) * 16384;        // current buffer
        char* pN = smem + ((t + 1) & 1) * 16384;  // next buffer

        // issue next-step staging loads (latency hidden under MFMA)
        ushort4 uhi, ulo;
        if (t < TT - 1) {
            uhi = *(const ushort4*)(ehi + (size_t)idxA * 128 + sk);
            ulo = *(const ushort4*)(elo + (size_t)idxA * 128 + sk);
            if (t < TT - 2) idxA = Xrow[teff(t + 2)];
        }

        f32x4 aR  = (f32x4){0.f, 0.f, 0.f, 0.f};
        f32x4 aZ  = (f32x4){0.f, 0.f, 0.f, 0.f};
        f32x4 aNX = (f32x4){0.f, 0.f, 0.f, 0.f};
        f32x4 aNH = (f32x4){0.f, 0.f, 0.f, 0.f};
        #pragma unroll
        for (int kc = 0; kc < 8; kc++) {
            int ao = (abase + kc * 64) ^ amask;
            short8 ah = *(const short8*)(pA + ao);
            short8 al = *(const short8*)(pA + 8192 + ao);
            int bo = bbase + kc * 32;
            short8 bhR = *(const short8*)(Whi + bo);
            short8 bhZ = *(const short8*)(Whi + bo + 128 * 256);
            short8 bhN = *(const short8*)(Whi + bo + 256 * 256);
            short8 blR = *(const short8*)(Wlo + bo);
            short8 blZ = *(const short8*)(Wlo + bo + 128 * 256);
            short8 blN = *(const short8*)(Wlo + bo + 256 * 256);
            f32x4& an = (kc < 4) ? aNX : aNH;
            aR = __builtin_amdgcn_mfma_f32_16x16x32_bf16(ah, bhR, aR, 0, 0, 0);
            aZ = __builtin_amdgcn_mfma_f32_16x16x32_bf16(ah, bhZ, aZ, 0, 0, 0);
            an = __builtin_amdgcn_mfma_f32_16x16x32_bf16(ah, bhN, an, 0, 0, 0);
            aR = __builtin_amdgcn_mfma_f32_16x16x32_bf16(al, bhR, aR, 0, 0, 0);
            aZ = __builtin_amdgcn_mfma_f32_16x16x32_bf16(al, bhZ, aZ, 0, 0, 0);
            an = __builtin_amdgcn_mfma_f32_16x16x32_bf16(al, bhN, an, 0, 0, 0);
            aR = __builtin_amdgcn_mfma_f32_16x16x32_bf16(ah, blR, aR, 0, 0, 0);
            aZ = __builtin_amdgcn_mfma_f32_16x16x32_bf16(ah, blZ, aZ, 0, 0, 0);
            an = __builtin_amdgcn_mfma_f32_16x16x32_bf16(ah, blN, an, 0, 0, 0);
        }

        // gates + h carry; h(t+1) goes to NEXT buffer (packed b32 writes)
        #pragma unroll
        for (int rr = 0; rr < 4; rr++) {
            int nl = l4 * 4 + rr;      // local node (C/D row map)
            float r = 1.f / (1.f + __expf(-(aR[rr] + bR)));
            float z = 1.f / (1.f + __expf(-(aZ[rr] + bZ)));
            float p = aNX[rr] + bXN + r * (aNH[rr] + bHN);
            float n = 1.f - 2.f / (__expf(2.f * p) + 1.f);   // tanh, overflow-safe
            float h = (1.f - z) * n + z * hprev[rr];
            hprev[rr] = h;
            unsigned short hh = f2bf(h);
            unsigned short ll = f2bf(h - bf2f(hh));
            unsigned pk = (unsigned)hh | ((unsigned)ll << 16);
            unsigned pp = __shfl_xor(pk, 1);
            if ((l15 & 1) == 0) {      // even lane writes the (j, j+1) pair
                unsigned hiw = (pk & 0xFFFFu) | (pp << 16);
                unsigned low = (pk >> 16) | (pp & 0xFFFF0000u);
                int hb = (nl * 512 + 256 + 2 * jd) ^ ((nl & 7) << 4);
                *(unsigned*)(pN + hb) = hiw;
                *(unsigned*)(pN + 8192 + hb) = low;
            }
            int node = base + nl;
            if (node < N) {
                q_out[((size_t)t * N + node) * 256 + dir * 128 + j] = h;
                if (t == TT - 1)
                    qn_out[(size_t)node * 256 + dir * 128 + j] = h;
            }
        }
        // write staged x(t+1) into next buffer
        if (t < TT - 1) {
            *(ushort4*)(pN + sb)        = uhi;
            *(ushort4*)(pN + 8192 + sb) = ulo;
        }
    }
}

// ---------- GAT: h = g @ Wg.T (fp32) ----------
__global__ __launch_bounds__(256, 2)
void gat_matmul(const float* __restrict__ G, const float* __restrict__ Wgt,
                float* __restrict__ Hout, int N) {
    const int base = blockIdx.x * 64;
    const int tid = threadIdx.x;
    const int tj = tid & 63;
    const int tn = tid >> 6;
    const int nb = tn * 16;
    __shared__ float A[256][68];

    const int snn = tid >> 2, sk4 = tid & 3;
    int node_s = base + snn; if (node_s >= N) node_s = N - 1;
    const float4* gr = (const float4*)(G + (size_t)node_s * 256);
    #pragma unroll
    for (int i = 0; i < 16; i++) {
        float4 v = gr[sk4 + 4 * i];
        int k = (sk4 + 4 * i) * 4;
        A[k + 0][snn] = v.x; A[k + 1][snn] = v.y;
        A[k + 2][snn] = v.z; A[k + 3][snn] = v.w;
    }
    __syncthreads();
    float acc0[16], acc1[16], acc2[16], acc3[16];
    #pragma unroll
    for (int i = 0; i < 16; i++) { acc0[i]=0.f; acc1[i]=0.f; acc2[i]=0.f; acc3[i]=0.f; }
    #pragma unroll 4
    for (int k = 0; k < 256; k++) {
        const float* wr = Wgt + k * 256;
        float w0 = wr[tj], w1 = wr[tj + 64], w2 = wr[tj + 128], w3 = wr[tj + 192];
        const float4* ar = (const float4*)&A[k][nb];
        float4 a0 = ar[0], a1 = ar[1], a2 = ar[2], a3 = ar[3];
        float av[16] = {a0.x, a0.y, a0.z, a0.w, a1.x, a1.y, a1.z, a1.w,
                        a2.x, a2.y, a2.z, a2.w, a3.x, a3.y, a3.z, a3.w};
        #pragma unroll
        for (int i = 0; i < 16; i++) {
            float a = av[i];
            acc0[i] += a * w0; acc1[i] += a * w1; acc2[i] += a * w2; acc3[i] += a * w3;
        }
    }
    #pragma unroll
    for (int i = 0; i < 16; i++) {
        int node = base + nb + i;
        if (node < N) {
            float* hp = Hout + (size_t)node * 256;
            hp[tj] = acc0[i]; hp[tj + 64] = acc1[i];
            hp[tj + 128] = acc2[i]; hp[tj + 192] = acc3[i];
        }
    }
}

// ---------- GAT: attention dots + per-node init ----------
__global__ void gat_dots(const float* __restrict__ Hm, const float* __restrict__ att_src,
                         const float* __restrict__ att_dst, float* __restrict__ a_src,
                         float* __restrict__ a_dst, unsigned* __restrict__ mx,
                         float* __restrict__ denom, int N) {
    int node = blockIdx.x * 4 + (threadIdx.x >> 6);
    int lane = threadIdx.x & 63;
    if (node >= N) return;
    const float* hr = Hm + (size_t)node * 256;
    float s1 = 0.f, s2 = 0.f;
    #pragma unroll
    for (int c = 0; c < 4; c++) {
        float h = hr[lane + 64 * c];
        s1 += h * att_src[lane + 64 * c];
        s2 += h * att_dst[lane + 64 * c];
    }
    #pragma unroll
    for (int o = 32; o > 0; o >>= 1) { s1 += __shfl_down(s1, o); s2 += __shfl_down(s2, o); }
    if (lane == 0) {
        a_src[node] = s1; a_dst[node] = s2;
        mx[node] = ENC_NEG_INF; denom[node] = 0.f;
    }
}

__global__ void edge_max(const int* __restrict__ src, const int* __restrict__ dst,
                         const float* __restrict__ a_src, const float* __restrict__ a_dst,
                         unsigned* __restrict__ mx, int E) {
    int i = blockIdx.x * 256 + threadIdx.x;
    if (i >= E) return;
    float v = a_src[src[i]] + a_dst[dst[i]];
    v = v > 0.f ? v : 0.2f * v;
    atomicMax(mx + dst[i], fenc(v));
}

__global__ void edge_exp(const int* __restrict__ src, const int* __restrict__ dst,
                         const float* __restrict__ a_src, const float* __restrict__ a_dst,
                         const unsigned* __restrict__ mx, float* __restrict__ denom,
                         const int* __restrict__ pos_of_edge, float* __restrict__ ex_sorted,
                         int E) {
    int i = blockIdx.x * 256 + threadIdx.x;
    if (i >= E) return;
    float v = a_src[src[i]] + a_dst[dst[i]];
    v = v > 0.f ? v : 0.2f * v;
    float e = __expf(v - fdec(mx[dst[i]]));
    atomicAdd(denom + dst[i], e);
    ex_sorted[pos_of_edge[i]] = e;
}

// ---------- GAT: CSR aggregate, one node per block ----------
__global__ void gat_aggregate(const float* __restrict__ Hm, const int* __restrict__ off,
                              const int* __restrict__ srcs_sorted,
                              const float* __restrict__ ex_sorted,
                              const float* __restrict__ denom, const float* __restrict__ bias,
                              float* __restrict__ Gout, int N) {
    int n = blockIdx.x;
    if (n >= N) return;
    int c = threadIdx.x;
    int s0 = off[n], s1 = off[n + 1];
    float acc = 0.f;
    for (int e = s0; e < s1; e++) {
        int s = srcs_sorted[e];
        float wgt = ex_sorted[e];
        acc += Hm[(size_t)s * 256 + c] * wgt;
    }
    float inv = (s1 > s0) ? 1.f / denom[n] : 0.f;
    Gout[(size_t)n * 256 + c] = acc * inv + bias[c];
}

// ---------- CSR build ----------
__global__ void zero_int(int* p, int n) {
    int i = blockIdx.x * 256 + threadIdx.x;
    if (i < n) p[i] = 0;
}
__global__ void deg_count(const int* __restrict__ dst, int* __restrict__ deg, int E) {
    int i = blockIdx.x * 256 + threadIdx.x;
    if (i < E) atomicAdd(deg + dst[i], 1);
}
__global__ void scan_k(const int* __restrict__ deg, int* __restrict__ off,
                       int* __restrict__ cursor, int n) {
    __shared__ int buf[256];
    __shared__ int carry_s;
    int tid = threadIdx.x;
    if (tid == 0) carry_s = 0;
    __syncthreads();
    for (int base = 0; base < n; base += 256) {
        int v = (base + tid < n) ? deg[base + tid] : 0;
        buf[tid] = v;
        __syncthreads();
        int x = v;
        for (int s = 1; s < 256; s <<= 1) {
            int tv = (tid >= s) ? buf[tid - s] : 0;
            __syncthreads();
            x += tv; buf[tid] = x;
            __syncthreads();
        }
        int carry = carry_s;
        if (base + tid < n) { off[base + tid] = carry + x - v; cursor[base + tid] = carry + x - v; }
        __syncthreads();
        if (tid == 255) carry_s = carry + x;
        __syncthreads();
    }
    if (tid == 0) off[n] = carry_s;
}
__global__ void scatter_k(const int* __restrict__ src, const int* __restrict__ dst,
                          int* __restrict__ cursor, int* __restrict__ srcs_sorted,
                          int* __restrict__ pos_of_edge, int E) {
    int i = blockIdx.x * 256 + threadIdx.x;
    if (i >= E) return;
    int p = atomicAdd(cursor + dst[i], 1);
    srcs_sorted[p] = src[i];
    pos_of_edge[i] = p;
}

// ---------- launch ----------
extern "C" void kernel_launch(void* const* d_in, const int* in_sizes, int n_in,
                              void* d_out, int out_size, void* d_ws, size_t ws_size,
                              hipStream_t stream) {
    const int N = in_sizes[0] / TT;
    const int E = in_sizes[1] / 2;
    const int EMBN = in_sizes[2];          // V * 128

    const int* X         = (const int*)d_in[0];
    const int* ei        = (const int*)d_in[1];
    const int* srcp      = ei;
    const int* dstp      = ei + E;
    const float* emb     = (const float*)d_in[2];
    const float* Wih_f   = (const float*)d_in[3];
    const float* Whh_f   = (const float*)d_in[4];
    const float* bih_f   = (const float*)d_in[5];
    const float* bhh_f   = (const float*)d_in[6];
    const float* Wih_b   = (const float*)d_in[7];
    const float* Whh_b   = (const float*)d_in[8];
    const float* bih_b   = (const float*)d_in[9];
    const float* bhh_b   = (const float*)d_in[10];
    const float* Wg      = (const float*)d_in[11];
    const float* att_src = (const float*)d_in[12];
    const float* att_dst = (const float*)d_in[13];
    const float* bg      = (const float*)d_in[14];

    float* out     = (float*)d_out;
    float* g_final = out;
    float* qn      = out + (size_t)N * 256;
    float* q       = out + (size_t)2 * N * 256;

    // ws layout
    float* w = (float*)d_ws;
    unsigned short* Whi_f = (unsigned short*)w; w += 49152;  // 384*256 ushort
    unsigned short* Wlo_f = (unsigned short*)w; w += 49152;
    unsigned short* Whi_b = (unsigned short*)w; w += 49152;
    unsigned short* Wlo_b = (unsigned short*)w; w += 49152;
    unsigned short* ehi   = (unsigned short*)w; w += (EMBN + 1) / 2;
    unsigned short* elo   = (unsigned short*)w; w += (EMBN + 1) / 2;
    float* Wgt   = w; w += 256 * 256;
    float* bufA  = w; w += (size_t)N * 256;
    float* bufB  = w; w += (size_t)N * 256;
    float* Hbuf  = w; w += (size_t)N * 256;
    float* a_src = w; w += N;
    float* a_dst = w; w += N;
    float* denom = w; w += N;
    unsigned* mx = (unsigned*)w; w += N;
    float* ex_sorted = w; w += E;
    int* iw = (int*)w;
    int* deg         = iw; iw += N;
    int* cursor      = iw; iw += N;
    int* off         = iw; iw += N + 1;
    int* srcs_sorted = iw; iw += E;
    int* pos_of_edge = iw; iw += E;

    // 1. weight + emb plane prep
    prep_w<<<384, 256, 0, stream>>>(Wih_f, Whh_f, Wih_b, Whh_b, Wg,
                                    Whi_f, Wlo_f, Whi_b, Wlo_b, Wgt);
    prep_emb<<<(EMBN + 255) / 256, 256, 0, stream>>>(emb, ehi, elo, EMBN);
    // 2. fused biGRU (MFMA, high occupancy), writes q and q_n
    dim3 ggrid((N + NB - 1) / NB, 2);
    gru_kernel<<<ggrid, 512, 0, stream>>>(X, ehi, elo, Whi_f, Wlo_f, Whi_b, Wlo_b,
                                          bih_f, bhh_f, bih_b, bhh_b, q, qn, N);
    // 3. CSR build (once, reused by all 4 layers)
    zero_int<<<(N + 255) / 256, 256, 0, stream>>>(deg, N);
    deg_count<<<(E + 255) / 256, 256, 0, stream>>>(dstp, deg, E);
    scan_k<<<1, 256, 0, stream>>>(deg, off, cursor, N);
    scatter_k<<<(E + 255) / 256, 256, 0, stream>>>(srcp, dstp, cursor, srcs_sorted,
                                                   pos_of_edge, E);
    // 4. 4 GAT layers (shared weights)
    const float* gin = qn;
    float* gouts[4] = {bufA, bufB, bufA, g_final};
    for (int l = 0; l < 4; l++) {
        gat_matmul<<<(N + 63) / 64, 256, 0, stream>>>(gin, Wgt, Hbuf, N);
        gat_dots<<<(N + 3) / 4, 256, 0, stream>>>(Hbuf, att_src, att_dst, a_src, a_dst,
                                                  mx, denom, N);
        edge_max<<<(E + 255) / 256, 256, 0, stream>>>(srcp, dstp, a_src, a_dst, mx, E);
        edge_exp<<<(E + 255) / 256, 256, 0, stream>>>(srcp, dstp, a_src, a_dst, mx, denom,
                                                      pos_of_edge, ex_sorted, E);
        gat_aggregate<<<N, 256, 0, stream>>>(Hbuf, off, srcs_sorted, ex_sorted, denom, bg,
                                             gouts[l], N);
        gin = gouts[l];
    }
}

// Round 11
// 3021.941 us; speedup vs baseline: 2.0606x; 2.0606x over previous
//
#include <hip/hip_runtime.h>

#define TT 32
#define NB 64   // nodes per GRU block (4 M-tiles of 16 per wave)

typedef __attribute__((ext_vector_type(8))) short short8;
typedef __attribute__((ext_vector_type(4))) float f32x4;

// ---------- helpers ----------
__device__ __host__ inline unsigned short f2bf(float f) {
    unsigned u = __float_as_uint(f);
    return (unsigned short)((u + 0x7FFFu + ((u >> 16) & 1u)) >> 16);
}
__device__ inline float bf2f(unsigned short h) {
    return __uint_as_float(((unsigned)h) << 16);
}
__device__ inline unsigned fenc(float f) {
    unsigned b = __float_as_uint(f);
    return (b & 0x80000000u) ? ~b : (b | 0x80000000u);
}
__device__ inline float fdec(unsigned u) {
    unsigned b = (u & 0x80000000u) ? (u & 0x7FFFFFFFu) : ~u;
    return __uint_as_float(b);
}
#define ENC_NEG_INF 0x007FFFFFu   // fenc(-inf)

// ---------- weight prep ----------
__global__ void prep_w(const float* __restrict__ Wih_f, const float* __restrict__ Whh_f,
                       const float* __restrict__ Wih_b, const float* __restrict__ Whh_b,
                       const float* __restrict__ Wg,
                       unsigned short* __restrict__ Whi_f, unsigned short* __restrict__ Wlo_f,
                       unsigned short* __restrict__ Whi_b, unsigned short* __restrict__ Wlo_b,
                       float* __restrict__ Wgt) {
    int i = blockIdx.x * 256 + threadIdx.x;
    if (i < 384 * 256) {
        int col = i / 256, k = i % 256;
        float ff = (k < 128) ? Wih_f[col * 128 + k] : Whh_f[col * 128 + (k - 128)];
        float fb = (k < 128) ? Wih_b[col * 128 + k] : Whh_b[col * 128 + (k - 128)];
        unsigned short hf = f2bf(ff);
        Whi_f[i] = hf; Wlo_f[i] = f2bf(ff - bf2f(hf));
        unsigned short hb = f2bf(fb);
        Whi_b[i] = hb; Wlo_b[i] = f2bf(fb - bf2f(hb));
    }
    if (i < 256 * 256) {
        int k = i / 256, j = i % 256;
        Wgt[i] = Wg[j * 256 + k];
    }
}

// ---------- emb bf16 hi/lo plane prep ----------
__global__ void prep_emb(const float* __restrict__ emb, unsigned short* __restrict__ ehi,
                         unsigned short* __restrict__ elo, int n) {
    int i = blockIdx.x * 256 + threadIdx.x;
    if (i < n) {
        float e = emb[i];
        unsigned short h = f2bf(e);
        ehi[i] = h; elo[i] = f2bf(e - bf2f(h));
    }
}

// ---------- fused biGRU: 64 nodes/block, 4 M-tiles/wave, B amortized ----------
// 512 threads = 8 waves. Wave w owns cols [16w,16w+16) of each gate (r,z,n);
// each wave computes FOUR 16-node M-tiles per step, so the 48 B-fragment
// L2 loads per step feed 288 MFMAs (6 MFMA/load vs 1.5 at NB=16 — R8/R9
// post-mortem: step time is B-load-latency-bound, so amortize).
// R10 post-mortem: staging used ushort4 (8B) where 16B chunks were needed —
// half the x-region never written -> NaN. Fixed: uint4 (16B) chunks.
// A (LDS, single 64KB buffer): [64 node][256 k] bf16 hi+lo planes, XOR-swizzled
// (byte ^= (row&7)<<4). k<128 = x_t, k>=128 = h. Two barriers/step.
// fp32 h carry: 16 regs/lane. x(t+1) loads issued before MFMA phase.
__global__ __launch_bounds__(512, 2)
void gru_kernel(const int* __restrict__ X,
                const unsigned short* __restrict__ ehi, const unsigned short* __restrict__ elo,
                const unsigned short* __restrict__ Whi_f, const unsigned short* __restrict__ Wlo_f,
                const unsigned short* __restrict__ Whi_b, const unsigned short* __restrict__ Wlo_b,
                const float* __restrict__ bih_f, const float* __restrict__ bhh_f,
                const float* __restrict__ bih_b, const float* __restrict__ bhh_b,
                float* __restrict__ q_out, float* __restrict__ qn_out, int N) {
    const int dir  = blockIdx.y;
    const int base = blockIdx.x * NB;
    const int tid  = threadIdx.x;
    const int lane = tid & 63;
    const int w    = tid >> 6;      // wave 0..7
    const int l15  = lane & 15;
    const int l4   = lane >> 4;     // 0..3

    const unsigned short* __restrict__ Whi = dir ? Whi_b : Whi_f;
    const unsigned short* __restrict__ Wlo = dir ? Wlo_b : Wlo_f;
    const float* __restrict__ bih = dir ? bih_b : bih_f;
    const float* __restrict__ bhh = dir ? bhh_b : bhh_f;

    __shared__ __align__(16) char smem[65536];   // hi plane @0, lo plane @32768

    const int j = w * 16 + l15;        // owned output col (per gate)
    const float bR  = bih[j]       + bhh[j];
    const float bZ  = bih[j + 128] + bhh[j + 128];
    const float bXN = bih[j + 256];
    const float bHN = bhh[j + 256];

    // B-fragment base offsets (ushort index); kc adds kc*32
    const int bbase = j * 256 + l4 * 8;

    // A-frag read bases for 4 tiles: row = mt*16 + l15
    int aob[4], amask[4];
    #pragma unroll
    for (int mt = 0; mt < 4; mt++) {
        int row = mt * 16 + l15;
        aob[mt]   = row * 512 + l4 * 16;
        amask[mt] = (row & 7) << 4;
    }

    // zero h-region (rows 0..63, bytes 256..511 per row, both planes)
    for (int i = tid; i < 8192; i += 512) {
        int plane = i >> 12, idx = i & 4095;
        int row = idx >> 6, d = idx & 63;
        *(unsigned*)(smem + plane * 32768 + row * 512 + 256 + d * 4) = 0u;
    }

    // staging: thread -> (node snode, 16 k at sk); two 16B chunks per plane
    const int snode = tid >> 3;          // 0..63
    const int sk    = (tid & 7) * 16;    // 0..112
    const int smask = (snode & 7) << 4;
    const int sb0   = (snode * 512 + sk * 2) ^ smask;
    const int sb1   = (snode * 512 + sk * 2 + 16) ^ smask;
    int node_s = base + snode; if (node_s >= N) node_s = N - 1;
    const int* Xrow = X + (size_t)node_s * TT;
    auto teff = [&](int t) { return dir ? (TT - 1 - t) : t; };

    { // stage x(0)
        int idx0 = Xrow[teff(0)];
        const unsigned short* eh = ehi + (size_t)idx0 * 128 + sk;
        const unsigned short* el = elo + (size_t)idx0 * 128 + sk;
        *(uint4*)(smem + sb0)         = *(const uint4*)(eh);       // k sk..sk+7
        *(uint4*)(smem + sb1)         = *(const uint4*)(eh + 8);   // k sk+8..sk+15
        *(uint4*)(smem + 32768 + sb0) = *(const uint4*)(el);
        *(uint4*)(smem + 32768 + sb1) = *(const uint4*)(el + 8);
    }
    int idxA = Xrow[teff(1)];    // index for x(1), prefetched

    float hprev[4][4];
    #pragma unroll
    for (int mt = 0; mt < 4; mt++)
        #pragma unroll
        for (int rr = 0; rr < 4; rr++) hprev[mt][rr] = 0.f;

    const int jd = j & ~1;       // even col of the (j, j^1) pair

    for (int t = 0; t < TT; t++) {
        __syncthreads();   // x(t) + h(t) writes visible

        // issue next-step staging loads (latency hidden under MFMA phase)
        uint4 uh0, uh1, ul0, ul1;
        if (t < TT - 1) {
            const unsigned short* eh = ehi + (size_t)idxA * 128 + sk;
            const unsigned short* el = elo + (size_t)idxA * 128 + sk;
            uh0 = *(const uint4*)(eh);
            uh1 = *(const uint4*)(eh + 8);
            ul0 = *(const uint4*)(el);
            ul1 = *(const uint4*)(el + 8);
            if (t < TT - 2) idxA = Xrow[teff(t + 2)];
        }

        f32x4 aR[4], aZ[4], aNX[4], aNH[4];
        #pragma unroll
        for (int mt = 0; mt < 4; mt++) {
            aR[mt]  = (f32x4){0.f, 0.f, 0.f, 0.f};
            aZ[mt]  = (f32x4){0.f, 0.f, 0.f, 0.f};
            aNX[mt] = (f32x4){0.f, 0.f, 0.f, 0.f};
            aNH[mt] = (f32x4){0.f, 0.f, 0.f, 0.f};
        }
        #pragma unroll
        for (int kc = 0; kc < 8; kc++) {
            int bo = bbase + kc * 32;
            short8 bhR = *(const short8*)(Whi + bo);
            short8 bhZ = *(const short8*)(Whi + bo + 128 * 256);
            short8 bhN = *(const short8*)(Whi + bo + 256 * 256);
            short8 blR = *(const short8*)(Wlo + bo);
            short8 blZ = *(const short8*)(Wlo + bo + 128 * 256);
            short8 blN = *(const short8*)(Wlo + bo + 256 * 256);
            #pragma unroll
            for (int mt = 0; mt < 4; mt++) {
                int ao = (aob[mt] + kc * 64) ^ amask[mt];
                short8 ah = *(const short8*)(smem + ao);
                short8 al = *(const short8*)(smem + 32768 + ao);
                f32x4& an = (kc < 4) ? aNX[mt] : aNH[mt];
                aR[mt] = __builtin_amdgcn_mfma_f32_16x16x32_bf16(ah, bhR, aR[mt], 0, 0, 0);
                aZ[mt] = __builtin_amdgcn_mfma_f32_16x16x32_bf16(ah, bhZ, aZ[mt], 0, 0, 0);
                an     = __builtin_amdgcn_mfma_f32_16x16x32_bf16(ah, bhN, an, 0, 0, 0);
                aR[mt] = __builtin_amdgcn_mfma_f32_16x16x32_bf16(al, bhR, aR[mt], 0, 0, 0);
                aZ[mt] = __builtin_amdgcn_mfma_f32_16x16x32_bf16(al, bhZ, aZ[mt], 0, 0, 0);
                an     = __builtin_amdgcn_mfma_f32_16x16x32_bf16(al, bhN, an, 0, 0, 0);
                aR[mt] = __builtin_amdgcn_mfma_f32_16x16x32_bf16(ah, blR, aR[mt], 0, 0, 0);
                aZ[mt] = __builtin_amdgcn_mfma_f32_16x16x32_bf16(ah, blZ, aZ[mt], 0, 0, 0);
                an     = __builtin_amdgcn_mfma_f32_16x16x32_bf16(ah, blN, an, 0, 0, 0);
            }
        }
        __syncthreads();   // all A reads done; safe to overwrite

        // gates + h carry; h(t+1) and x(t+1) written into the (single) buffer
        #pragma unroll
        for (int mt = 0; mt < 4; mt++)
            #pragma unroll
            for (int rr = 0; rr < 4; rr++) {
                int nl = mt * 16 + l4 * 4 + rr;    // local node (C/D row map)
                float r = 1.f / (1.f + __expf(-(aR[mt][rr] + bR)));
                float z = 1.f / (1.f + __expf(-(aZ[mt][rr] + bZ)));
                float p = aNX[mt][rr] + bXN + r * (aNH[mt][rr] + bHN);
                float n = 1.f - 2.f / (__expf(2.f * p) + 1.f);   // tanh
                float h = (1.f - z) * n + z * hprev[mt][rr];
                hprev[mt][rr] = h;
                unsigned short hh = f2bf(h);
                unsigned short ll = f2bf(h - bf2f(hh));
                unsigned pk = (unsigned)hh | ((unsigned)ll << 16);
                unsigned pp = __shfl_xor(pk, 1);
                if ((l15 & 1) == 0) {      // even lane writes the (j, j+1) pair
                    unsigned hiw = (pk & 0xFFFFu) | (pp << 16);
                    unsigned low = (pk >> 16) | (pp & 0xFFFF0000u);
                    int hb = (nl * 512 + 256 + 2 * jd) ^ ((nl & 7) << 4);
                    *(unsigned*)(smem + hb) = hiw;
                    *(unsigned*)(smem + 32768 + hb) = low;
                }
                int node = base + nl;
                if (node < N) {
                    q_out[((size_t)t * N + node) * 256 + dir * 128 + j] = h;
                    if (t == TT - 1)
                        qn_out[(size_t)node * 256 + dir * 128 + j] = h;
                }
            }
        if (t < TT - 1) {
            *(uint4*)(smem + sb0)         = uh0;
            *(uint4*)(smem + sb1)         = uh1;
            *(uint4*)(smem + 32768 + sb0) = ul0;
            *(uint4*)(smem + 32768 + sb1) = ul1;
        }
    }
}

// ---------- GAT: h = g @ Wg.T (fp32) ----------
__global__ __launch_bounds__(256, 2)
void gat_matmul(const float* __restrict__ G, const float* __restrict__ Wgt,
                float* __restrict__ Hout, int N) {
    const int base = blockIdx.x * 64;
    const int tid = threadIdx.x;
    const int tj = tid & 63;
    const int tn = tid >> 6;
    const int nb = tn * 16;
    __shared__ float A[256][68];

    const int snn = tid >> 2, sk4 = tid & 3;
    int node_s = base + snn; if (node_s >= N) node_s = N - 1;
    const float4* gr = (const float4*)(G + (size_t)node_s * 256);
    #pragma unroll
    for (int i = 0; i < 16; i++) {
        float4 v = gr[sk4 + 4 * i];
        int k = (sk4 + 4 * i) * 4;
        A[k + 0][snn] = v.x; A[k + 1][snn] = v.y;
        A[k + 2][snn] = v.z; A[k + 3][snn] = v.w;
    }
    __syncthreads();
    float acc0[16], acc1[16], acc2[16], acc3[16];
    #pragma unroll
    for (int i = 0; i < 16; i++) { acc0[i]=0.f; acc1[i]=0.f; acc2[i]=0.f; acc3[i]=0.f; }
    #pragma unroll 4
    for (int k = 0; k < 256; k++) {
        const float* wr = Wgt + k * 256;
        float w0 = wr[tj], w1 = wr[tj + 64], w2 = wr[tj + 128], w3 = wr[tj + 192];
        const float4* ar = (const float4*)&A[k][nb];
        float4 a0 = ar[0], a1 = ar[1], a2 = ar[2], a3 = ar[3];
        float av[16] = {a0.x, a0.y, a0.z, a0.w, a1.x, a1.y, a1.z, a1.w,
                        a2.x, a2.y, a2.z, a2.w, a3.x, a3.y, a3.z, a3.w};
        #pragma unroll
        for (int i = 0; i < 16; i++) {
            float a = av[i];
            acc0[i] += a * w0; acc1[i] += a * w1; acc2[i] += a * w2; acc3[i] += a * w3;
        }
    }
    #pragma unroll
    for (int i = 0; i < 16; i++) {
        int node = base + nb + i;
        if (node < N) {
            float* hp = Hout + (size_t)node * 256;
            hp[tj] = acc0[i]; hp[tj + 64] = acc1[i];
            hp[tj + 128] = acc2[i]; hp[tj + 192] = acc3[i];
        }
    }
}

// ---------- GAT: attention dots + per-node init ----------
__global__ void gat_dots(const float* __restrict__ Hm, const float* __restrict__ att_src,
                         const float* __restrict__ att_dst, float* __restrict__ a_src,
                         float* __restrict__ a_dst, unsigned* __restrict__ mx,
                         float* __restrict__ denom, int N) {
    int node = blockIdx.x * 4 + (threadIdx.x >> 6);
    int lane = threadIdx.x & 63;
    if (node >= N) return;
    const float* hr = Hm + (size_t)node * 256;
    float s1 = 0.f, s2 = 0.f;
    #pragma unroll
    for (int c = 0; c < 4; c++) {
        float h = hr[lane + 64 * c];
        s1 += h * att_src[lane + 64 * c];
        s2 += h * att_dst[lane + 64 * c];
    }
    #pragma unroll
    for (int o = 32; o > 0; o >>= 1) { s1 += __shfl_down(s1, o); s2 += __shfl_down(s2, o); }
    if (lane == 0) {
        a_src[node] = s1; a_dst[node] = s2;
        mx[node] = ENC_NEG_INF; denom[node] = 0.f;
    }
}

__global__ void edge_max(const int* __restrict__ src, const int* __restrict__ dst,
                         const float* __restrict__ a_src, const float* __restrict__ a_dst,
                         unsigned* __restrict__ mx, int E) {
    int i = blockIdx.x * 256 + threadIdx.x;
    if (i >= E) return;
    float v = a_src[src[i]] + a_dst[dst[i]];
    v = v > 0.f ? v : 0.2f * v;
    atomicMax(mx + dst[i], fenc(v));
}

__global__ void edge_exp(const int* __restrict__ src, const int* __restrict__ dst,
                         const float* __restrict__ a_src, const float* __restrict__ a_dst,
                         const unsigned* __restrict__ mx, float* __restrict__ denom,
                         const int* __restrict__ pos_of_edge, float* __restrict__ ex_sorted,
                         int E) {
    int i = blockIdx.x * 256 + threadIdx.x;
    if (i >= E) return;
    float v = a_src[src[i]] + a_dst[dst[i]];
    v = v > 0.f ? v : 0.2f * v;
    float e = __expf(v - fdec(mx[dst[i]]));
    atomicAdd(denom + dst[i], e);
    ex_sorted[pos_of_edge[i]] = e;
}

// ---------- GAT: CSR aggregate, one node per block ----------
__global__ void gat_aggregate(const float* __restrict__ Hm, const int* __restrict__ off,
                              const int* __restrict__ srcs_sorted,
                              const float* __restrict__ ex_sorted,
                              const float* __restrict__ denom, const float* __restrict__ bias,
                              float* __restrict__ Gout, int N) {
    int n = blockIdx.x;
    if (n >= N) return;
    int c = threadIdx.x;
    int s0 = off[n], s1 = off[n + 1];
    float acc = 0.f;
    for (int e = s0; e < s1; e++) {
        int s = srcs_sorted[e];
        float wgt = ex_sorted[e];
        acc += Hm[(size_t)s * 256 + c] * wgt;
    }
    float inv = (s1 > s0) ? 1.f / denom[n] : 0.f;
    Gout[(size_t)n * 256 + c] = acc * inv + bias[c];
}

// ---------- CSR build ----------
__global__ void zero_int(int* p, int n) {
    int i = blockIdx.x * 256 + threadIdx.x;
    if (i < n) p[i] = 0;
}
__global__ void deg_count(const int* __restrict__ dst, int* __restrict__ deg, int E) {
    int i = blockIdx.x * 256 + threadIdx.x;
    if (i < E) atomicAdd(deg + dst[i], 1);
}
__global__ void scan_k(const int* __restrict__ deg, int* __restrict__ off,
                       int* __restrict__ cursor, int n) {
    __shared__ int buf[256];
    __shared__ int carry_s;
    int tid = threadIdx.x;
    if (tid == 0) carry_s = 0;
    __syncthreads();
    for (int base = 0; base < n; base += 256) {
        int v = (base + tid < n) ? deg[base + tid] : 0;
        buf[tid] = v;
        __syncthreads();
        int x = v;
        for (int s = 1; s < 256; s <<= 1) {
            int tv = (tid >= s) ? buf[tid - s] : 0;
            __syncthreads();
            x += tv; buf[tid] = x;
            __syncthreads();
        }
        int carry = carry_s;
        if (base + tid < n) { off[base + tid] = carry + x - v; cursor[base + tid] = carry + x - v; }
        __syncthreads();
        if (tid == 255) carry_s = carry + x;
        __syncthreads();
    }
    if (tid == 0) off[n] = carry_s;
}
__global__ void scatter_k(const int* __restrict__ src, const int* __restrict__ dst,
                          int* __restrict__ cursor, int* __restrict__ srcs_sorted,
                          int* __restrict__ pos_of_edge, int E) {
    int i = blockIdx.x * 256 + threadIdx.x;
    if (i >= E) return;
    int p = atomicAdd(cursor + dst[i], 1);
    srcs_sorted[p] = src[i];
    pos_of_edge[i] = p;
}

// ---------- launch ----------
extern "C" void kernel_launch(void* const* d_in, const int* in_sizes, int n_in,
                              void* d_out, int out_size, void* d_ws, size_t ws_size,
                              hipStream_t stream) {
    const int N = in_sizes[0] / TT;
    const int E = in_sizes[1] / 2;
    const int EMBN = in_sizes[2];          // V * 128

    const int* X         = (const int*)d_in[0];
    const int* ei        = (const int*)d_in[1];
    const int* srcp      = ei;
    const int* dstp      = ei + E;
    const float* emb     = (const float*)d_in[2];
    const float* Wih_f   = (const float*)d_in[3];
    const float* Whh_f   = (const float*)d_in[4];
    const float* bih_f   = (const float*)d_in[5];
    const float* bhh_f   = (const float*)d_in[6];
    const float* Wih_b   = (const float*)d_in[7];
    const float* Whh_b   = (const float*)d_in[8];
    const float* bih_b   = (const float*)d_in[9];
    const float* bhh_b   = (const float*)d_in[10];
    const float* Wg      = (const float*)d_in[11];
    const float* att_src = (const float*)d_in[12];
    const float* att_dst = (const float*)d_in[13];
    const float* bg      = (const float*)d_in[14];

    float* out     = (float*)d_out;
    float* g_final = out;
    float* qn      = out + (size_t)N * 256;
    float* q       = out + (size_t)2 * N * 256;

    // ws layout
    float* w = (float*)d_ws;
    unsigned short* Whi_f = (unsigned short*)w; w += 49152;  // 384*256 ushort
    unsigned short* Wlo_f = (unsigned short*)w; w += 49152;
    unsigned short* Whi_b = (unsigned short*)w; w += 49152;
    unsigned short* Wlo_b = (unsigned short*)w; w += 49152;
    unsigned short* ehi   = (unsigned short*)w; w += (EMBN + 1) / 2;
    unsigned short* elo   = (unsigned short*)w; w += (EMBN + 1) / 2;
    float* Wgt   = w; w += 256 * 256;
    float* bufA  = w; w += (size_t)N * 256;
    float* bufB  = w; w += (size_t)N * 256;
    float* Hbuf  = w; w += (size_t)N * 256;
    float* a_src = w; w += N;
    float* a_dst = w; w += N;
    float* denom = w; w += N;
    unsigned* mx = (unsigned*)w; w += N;
    float* ex_sorted = w; w += E;
    int* iw = (int*)w;
    int* deg         = iw; iw += N;
    int* cursor      = iw; iw += N;
    int* off         = iw; iw += N + 1;
    int* srcs_sorted = iw; iw += E;
    int* pos_of_edge = iw; iw += E;

    // 1. weight + emb plane prep
    prep_w<<<384, 256, 0, stream>>>(Wih_f, Whh_f, Wih_b, Whh_b, Wg,
                                    Whi_f, Wlo_f, Whi_b, Wlo_b, Wgt);
    prep_emb<<<(EMBN + 255) / 256, 256, 0, stream>>>(emb, ehi, elo, EMBN);
    // 2. fused biGRU (MFMA, 64 nodes/block), writes q and q_n
    dim3 ggrid((N + NB - 1) / NB, 2);
    gru_kernel<<<ggrid, 512, 0, stream>>>(X, ehi, elo, Whi_f, Wlo_f, Whi_b, Wlo_b,
                                          bih_f, bhh_f, bih_b, bhh_b, q, qn, N);
    // 3. CSR build (once, reused by all 4 layers)
    zero_int<<<(N + 255) / 256, 256, 0, stream>>>(deg, N);
    deg_count<<<(E + 255) / 256, 256, 0, stream>>>(dstp, deg, E);
    scan_k<<<1, 256, 0, stream>>>(deg, off, cursor, N);
    scatter_k<<<(E + 255) / 256, 256, 0, stream>>>(srcp, dstp, cursor, srcs_sorted,
                                                   pos_of_edge, E);
    // 4. 4 GAT layers (shared weights)
    const float* gin = qn;
    float* gouts[4] = {bufA, bufB, bufA, g_final};
    for (int l = 0; l < 4; l++) {
        gat_matmul<<<(N + 63) / 64, 256, 0, stream>>>(gin, Wgt, Hbuf, N);
        gat_dots<<<(N + 3) / 4, 256, 0, stream>>>(Hbuf, att_src, att_dst, a_src, a_dst,
                                                  mx, denom, N);
        edge_max<<<(E + 255) / 256, 256, 0, stream>>>(srcp, dstp, a_src, a_dst, mx, E);
        edge_exp<<<(E + 255) / 256, 256, 0, stream>>>(srcp, dstp, a_src, a_dst, mx, denom,
                                                      pos_of_edge, ex_sorted, E);
        gat_aggregate<<<N, 256, 0, stream>>>(Hbuf, off, srcs_sorted, ex_sorted, denom, bg,
                                             gouts[l], N);
        gin = gouts[l];
    }
}

// Round 12
// 1810.163 us; speedup vs baseline: 3.4401x; 1.6694x over previous
//
#include <hip/hip_runtime.h>

#define TT 32
#define NB 16   // nodes per GRU block

typedef __attribute__((ext_vector_type(8))) short short8;
typedef __attribute__((ext_vector_type(4))) float f32x4;

// ---------- helpers ----------
__device__ __host__ inline unsigned short f2bf(float f) {
    unsigned u = __float_as_uint(f);
    return (unsigned short)((u + 0x7FFFu + ((u >> 16) & 1u)) >> 16);
}
__device__ inline float bf2f(unsigned short h) {
    return __uint_as_float(((unsigned)h) << 16);
}
__device__ inline unsigned fenc(float f) {
    unsigned b = __float_as_uint(f);
    return (b & 0x80000000u) ? ~b : (b | 0x80000000u);
}
__device__ inline float fdec(unsigned u) {
    unsigned b = (u & 0x80000000u) ? (u & 0x7FFFFFFFu) : ~u;
    return __uint_as_float(b);
}
#define ENC_NEG_INF 0x007FFFFFu   // fenc(-inf)

// ---------- weight prep ----------
// GRU: W planes [384 col][256 k] bf16 hi/lo per dir. GAT: Wg planes
// [256 col][256 k] bf16 hi/lo (B[col][k] = Wg[col*256+k], no transpose).
__global__ void prep_w(const float* __restrict__ Wih_f, const float* __restrict__ Whh_f,
                       const float* __restrict__ Wih_b, const float* __restrict__ Whh_b,
                       const float* __restrict__ Wg,
                       unsigned short* __restrict__ Whi_f, unsigned short* __restrict__ Wlo_f,
                       unsigned short* __restrict__ Whi_b, unsigned short* __restrict__ Wlo_b,
                       unsigned short* __restrict__ Wghi, unsigned short* __restrict__ Wglo) {
    int i = blockIdx.x * 256 + threadIdx.x;
    if (i < 384 * 256) {
        int col = i / 256, k = i % 256;
        float ff = (k < 128) ? Wih_f[col * 128 + k] : Whh_f[col * 128 + (k - 128)];
        float fb = (k < 128) ? Wih_b[col * 128 + k] : Whh_b[col * 128 + (k - 128)];
        unsigned short hf = f2bf(ff);
        Whi_f[i] = hf; Wlo_f[i] = f2bf(ff - bf2f(hf));
        unsigned short hb = f2bf(fb);
        Whi_b[i] = hb; Wlo_b[i] = f2bf(fb - bf2f(hb));
    }
    if (i < 256 * 256) {
        float g = Wg[i];
        unsigned short h = f2bf(g);
        Wghi[i] = h; Wglo[i] = f2bf(g - bf2f(h));
    }
}

// ---------- emb bf16 hi/lo plane prep ----------
__global__ void prep_emb(const float* __restrict__ emb, unsigned short* __restrict__ ehi,
                         unsigned short* __restrict__ elo, int n) {
    int i = blockIdx.x * 256 + threadIdx.x;
    if (i < n) {
        float e = emb[i];
        unsigned short h = f2bf(e);
        ehi[i] = h; elo[i] = f2bf(e - bf2f(h));
    }
}

// ---------- fused biGRU: R5/R8 proven config (1020-1030 us) ----------
// 512 threads = 8 waves, 16 nodes/block, dbuf LDS, B streamed from L2.
__global__ __launch_bounds__(512, 1)
void gru_kernel(const int* __restrict__ X,
                const unsigned short* __restrict__ ehi, const unsigned short* __restrict__ elo,
                const unsigned short* __restrict__ Whi_f, const unsigned short* __restrict__ Wlo_f,
                const unsigned short* __restrict__ Whi_b, const unsigned short* __restrict__ Wlo_b,
                const float* __restrict__ bih_f, const float* __restrict__ bhh_f,
                const float* __restrict__ bih_b, const float* __restrict__ bhh_b,
                float* __restrict__ q_out, float* __restrict__ qn_out, int N) {
    const int dir  = blockIdx.y;
    const int base = blockIdx.x * NB;
    const int tid  = threadIdx.x;
    const int lane = tid & 63;
    const int w    = tid >> 6;      // wave 0..7
    const int l15  = lane & 15;
    const int l4   = lane >> 4;     // 0..3

    const unsigned short* __restrict__ Whi = dir ? Whi_b : Whi_f;
    const unsigned short* __restrict__ Wlo = dir ? Wlo_b : Wlo_f;
    const float* __restrict__ bih = dir ? bih_b : bih_f;
    const float* __restrict__ bhh = dir ? bhh_b : bhh_f;

    __shared__ __align__(16) char smem[32768];   // 2 buffers x (Ahi 8K + Alo 8K)

    const int j = w * 16 + l15;        // owned output col (per gate)
    const float bR  = bih[j]       + bhh[j];
    const float bZ  = bih[j + 128] + bhh[j + 128];
    const float bXN = bih[j + 256];
    const float bHN = bhh[j + 256];

    // B-fragment base offsets (ushort index); kc adds kc*32
    const int bbase = j * 256 + l4 * 8;

    // A-frag read base: row = l15, kbyte = kc*64 + l4*16
    const int amask = (l15 & 7) << 4;
    const int abase = l15 * 512 + l4 * 16;

    // zero h-region of buffer 0 (rows 0..15, bytes 256..511, both planes)
    for (int i = tid; i < 2048; i += 512) {
        int plane = i >> 10, idx = i & 1023;
        int row = idx >> 6, d = idx & 63;
        *(unsigned*)(smem + plane * 8192 + row * 512 + 256 + d * 4) = 0u;
    }

    // staging: thread -> (node snode, 4 k at sk); pure 8B+8B copy
    const int snode = tid >> 5;
    const int sk    = (tid & 31) * 4;
    const int sb    = (snode * 512 + sk * 2) ^ ((snode & 7) << 4);
    int node_s = base + snode; if (node_s >= N) node_s = N - 1;
    const int* Xrow = X + (size_t)node_s * TT;
    auto teff = [&](int t) { return dir ? (TT - 1 - t) : t; };

    { // stage x(0) into buffer 0
        int idx0 = Xrow[teff(0)];
        *(ushort4*)(smem + sb)        = *(const ushort4*)(ehi + (size_t)idx0 * 128 + sk);
        *(ushort4*)(smem + 8192 + sb) = *(const ushort4*)(elo + (size_t)idx0 * 128 + sk);
    }
    int idxA = Xrow[teff(1)];    // index for x(1), prefetched

    float hprev[4] = {0.f, 0.f, 0.f, 0.f};
    const int jd = j & ~1;       // even col of the (j, j^1) pair

    for (int t = 0; t < TT; t++) {
        __syncthreads();   // buf[cur] (x_t + h_t) fully written

        char* pA = smem + (t & 1) * 16384;        // current buffer
        char* pN = smem + ((t + 1) & 1) * 16384;  // next buffer

        // issue next-step staging loads (latency hidden under MFMA)
        ushort4 uhi, ulo;
        if (t < TT - 1) {
            uhi = *(const ushort4*)(ehi + (size_t)idxA * 128 + sk);
            ulo = *(const ushort4*)(elo + (size_t)idxA * 128 + sk);
            if (t < TT - 2) idxA = Xrow[teff(t + 2)];
        }

        f32x4 aR  = (f32x4){0.f, 0.f, 0.f, 0.f};
        f32x4 aZ  = (f32x4){0.f, 0.f, 0.f, 0.f};
        f32x4 aNX = (f32x4){0.f, 0.f, 0.f, 0.f};
        f32x4 aNH = (f32x4){0.f, 0.f, 0.f, 0.f};
        #pragma unroll
        for (int kc = 0; kc < 8; kc++) {
            int ao = (abase + kc * 64) ^ amask;
            short8 ah = *(const short8*)(pA + ao);
            short8 al = *(const short8*)(pA + 8192 + ao);
            int bo = bbase + kc * 32;
            short8 bhR = *(const short8*)(Whi + bo);
            short8 bhZ = *(const short8*)(Whi + bo + 128 * 256);
            short8 bhN = *(const short8*)(Whi + bo + 256 * 256);
            short8 blR = *(const short8*)(Wlo + bo);
            short8 blZ = *(const short8*)(Wlo + bo + 128 * 256);
            short8 blN = *(const short8*)(Wlo + bo + 256 * 256);
            f32x4& an = (kc < 4) ? aNX : aNH;
            aR = __builtin_amdgcn_mfma_f32_16x16x32_bf16(ah, bhR, aR, 0, 0, 0);
            aZ = __builtin_amdgcn_mfma_f32_16x16x32_bf16(ah, bhZ, aZ, 0, 0, 0);
            an = __builtin_amdgcn_mfma_f32_16x16x32_bf16(ah, bhN, an, 0, 0, 0);
            aR = __builtin_amdgcn_mfma_f32_16x16x32_bf16(al, bhR, aR, 0, 0, 0);
            aZ = __builtin_amdgcn_mfma_f32_16x16x32_bf16(al, bhZ, aZ, 0, 0, 0);
            an = __builtin_amdgcn_mfma_f32_16x16x32_bf16(al, bhN, an, 0, 0, 0);
            aR = __builtin_amdgcn_mfma_f32_16x16x32_bf16(ah, blR, aR, 0, 0, 0);
            aZ = __builtin_amdgcn_mfma_f32_16x16x32_bf16(ah, blZ, aZ, 0, 0, 0);
            an = __builtin_amdgcn_mfma_f32_16x16x32_bf16(ah, blN, an, 0, 0, 0);
        }

        // gates + h carry; h(t+1) goes to NEXT buffer (packed b32 writes)
        #pragma unroll
        for (int rr = 0; rr < 4; rr++) {
            int nl = l4 * 4 + rr;      // local node (C/D row map)
            float r = 1.f / (1.f + __expf(-(aR[rr] + bR)));
            float z = 1.f / (1.f + __expf(-(aZ[rr] + bZ)));
            float p = aNX[rr] + bXN + r * (aNH[rr] + bHN);
            float n = 1.f - 2.f / (__expf(2.f * p) + 1.f);   // tanh, overflow-safe
            float h = (1.f - z) * n + z * hprev[rr];
            hprev[rr] = h;
            unsigned short hh = f2bf(h);
            unsigned short ll = f2bf(h - bf2f(hh));
            unsigned pk = (unsigned)hh | ((unsigned)ll << 16);
            unsigned pp = __shfl_xor(pk, 1);
            if ((l15 & 1) == 0) {      // even lane writes the (j, j+1) pair
                unsigned hiw = (pk & 0xFFFFu) | (pp << 16);
                unsigned low = (pk >> 16) | (pp & 0xFFFF0000u);
                int hb = (nl * 512 + 256 + 2 * jd) ^ ((nl & 7) << 4);
                *(unsigned*)(pN + hb) = hiw;
                *(unsigned*)(pN + 8192 + hb) = low;
            }
            int node = base + nl;
            if (node < N) {
                q_out[((size_t)t * N + node) * 256 + dir * 128 + j] = h;
                if (t == TT - 1)
                    qn_out[(size_t)node * 256 + dir * 128 + j] = h;
            }
        }
        // write staged x(t+1) into next buffer
        if (t < TT - 1) {
            *(ushort4*)(pN + sb)        = uhi;
            *(ushort4*)(pN + 8192 + sb) = ulo;
        }
    }
}

// ---------- GAT: h = g @ Wg.T via bf16 MFMA 3-pass ----------
// 256 threads = 4 waves, 32 nodes/block (2 M-tiles). Wave w owns cols
// [64w, 64w+64) = 4 col-tiles of 16. A staged fp32->bf16 hi/lo in LDS
// (same XOR swizzle as GRU, verified). B streamed from L2 (128KB planes).
__global__ __launch_bounds__(256)
void gat_matmul(const float* __restrict__ G,
                const unsigned short* __restrict__ Wghi, const unsigned short* __restrict__ Wglo,
                float* __restrict__ Hout, int N) {
    const int base = blockIdx.x * 32;
    const int tid  = threadIdx.x;
    const int lane = tid & 63;
    const int w    = tid >> 6;      // wave 0..3
    const int l15  = lane & 15;
    const int l4   = lane >> 4;

    __shared__ __align__(16) char smem[32768];   // hi @0, lo @16384

    // staging: snode = tid>>3 (0..31), sk = (tid&7)*32 (k per thread: 32)
    const int snode = tid >> 3;
    const int sk    = (tid & 7) * 32;
    const int smask = (snode & 7) << 4;
    int node_s = base + snode; if (node_s >= N) node_s = N - 1;
    const float* gr = G + (size_t)node_s * 256 + sk;
    #pragma unroll
    for (int c = 0; c < 4; c++) {
        float4 v0 = *(const float4*)(gr + c * 8);
        float4 v1 = *(const float4*)(gr + c * 8 + 4);
        unsigned short h0 = f2bf(v0.x), h1 = f2bf(v0.y), h2 = f2bf(v0.z), h3 = f2bf(v0.w);
        unsigned short h4 = f2bf(v1.x), h5 = f2bf(v1.y), h6 = f2bf(v1.z), h7 = f2bf(v1.w);
        uint4 hi = {(unsigned)h0 | ((unsigned)h1 << 16), (unsigned)h2 | ((unsigned)h3 << 16),
                    (unsigned)h4 | ((unsigned)h5 << 16), (unsigned)h6 | ((unsigned)h7 << 16)};
        uint4 lo = {(unsigned)f2bf(v0.x - bf2f(h0)) | ((unsigned)f2bf(v0.y - bf2f(h1)) << 16),
                    (unsigned)f2bf(v0.z - bf2f(h2)) | ((unsigned)f2bf(v0.w - bf2f(h3)) << 16),
                    (unsigned)f2bf(v1.x - bf2f(h4)) | ((unsigned)f2bf(v1.y - bf2f(h5)) << 16),
                    (unsigned)f2bf(v1.z - bf2f(h6)) | ((unsigned)f2bf(v1.w - bf2f(h7)) << 16)};
        int addr = (snode * 512 + (sk + c * 8) * 2) ^ smask;
        *(uint4*)(smem + addr) = hi;
        *(uint4*)(smem + 16384 + addr) = lo;
    }
    __syncthreads();

    // A-frag bases for 2 M-tiles
    int aob[2], amask[2];
    #pragma unroll
    for (int mt = 0; mt < 2; mt++) {
        int row = mt * 16 + l15;
        aob[mt]   = row * 512 + l4 * 16;
        amask[mt] = (row & 7) << 4;
    }
    // B-frag bases for 4 col-tiles
    int bb[4];
    #pragma unroll
    for (int th = 0; th < 4; th++)
        bb[th] = (w * 64 + th * 16 + l15) * 256 + l4 * 8;

    f32x4 acc[4][2];
    #pragma unroll
    for (int th = 0; th < 4; th++)
        #pragma unroll
        for (int mt = 0; mt < 2; mt++) acc[th][mt] = (f32x4){0.f, 0.f, 0.f, 0.f};

    #pragma unroll
    for (int kc = 0; kc < 8; kc++) {
        short8 ah[2], al[2];
        #pragma unroll
        for (int mt = 0; mt < 2; mt++) {
            int ao = (aob[mt] + kc * 64) ^ amask[mt];
            ah[mt] = *(const short8*)(smem + ao);
            al[mt] = *(const short8*)(smem + 16384 + ao);
        }
        #pragma unroll
        for (int th = 0; th < 4; th++) {
            int bo = bb[th] + kc * 32;
            short8 bh = *(const short8*)(Wghi + bo);
            short8 bl = *(const short8*)(Wglo + bo);
            #pragma unroll
            for (int mt = 0; mt < 2; mt++) {
                acc[th][mt] = __builtin_amdgcn_mfma_f32_16x16x32_bf16(ah[mt], bh, acc[th][mt], 0, 0, 0);
                acc[th][mt] = __builtin_amdgcn_mfma_f32_16x16x32_bf16(al[mt], bh, acc[th][mt], 0, 0, 0);
                acc[th][mt] = __builtin_amdgcn_mfma_f32_16x16x32_bf16(ah[mt], bl, acc[th][mt], 0, 0, 0);
            }
        }
    }

    #pragma unroll
    for (int th = 0; th < 4; th++)
        #pragma unroll
        for (int mt = 0; mt < 2; mt++)
            #pragma unroll
            for (int rr = 0; rr < 4; rr++) {
                int node = base + mt * 16 + l4 * 4 + rr;
                int col  = w * 64 + th * 16 + l15;
                if (node < N) Hout[(size_t)node * 256 + col] = acc[th][mt][rr];
            }
}

// ---------- GAT: attention dots + per-node init ----------
__global__ void gat_dots(const float* __restrict__ Hm, const float* __restrict__ att_src,
                         const float* __restrict__ att_dst, float* __restrict__ a_src,
                         float* __restrict__ a_dst, unsigned* __restrict__ mx,
                         float* __restrict__ denom, int N) {
    int node = blockIdx.x * 4 + (threadIdx.x >> 6);
    int lane = threadIdx.x & 63;
    if (node >= N) return;
    const float* hr = Hm + (size_t)node * 256;
    float s1 = 0.f, s2 = 0.f;
    #pragma unroll
    for (int c = 0; c < 4; c++) {
        float h = hr[lane + 64 * c];
        s1 += h * att_src[lane + 64 * c];
        s2 += h * att_dst[lane + 64 * c];
    }
    #pragma unroll
    for (int o = 32; o > 0; o >>= 1) { s1 += __shfl_down(s1, o); s2 += __shfl_down(s2, o); }
    if (lane == 0) {
        a_src[node] = s1; a_dst[node] = s2;
        mx[node] = ENC_NEG_INF; denom[node] = 0.f;
    }
}

__global__ void edge_max(const int* __restrict__ src, const int* __restrict__ dst,
                         const float* __restrict__ a_src, const float* __restrict__ a_dst,
                         unsigned* __restrict__ mx, int E) {
    int i = blockIdx.x * 256 + threadIdx.x;
    if (i >= E) return;
    float v = a_src[src[i]] + a_dst[dst[i]];
    v = v > 0.f ? v : 0.2f * v;
    atomicMax(mx + dst[i], fenc(v));
}

__global__ void edge_exp(const int* __restrict__ src, const int* __restrict__ dst,
                         const float* __restrict__ a_src, const float* __restrict__ a_dst,
                         const unsigned* __restrict__ mx, float* __restrict__ denom,
                         const int* __restrict__ pos_of_edge, float* __restrict__ ex_sorted,
                         int E) {
    int i = blockIdx.x * 256 + threadIdx.x;
    if (i >= E) return;
    float v = a_src[src[i]] + a_dst[dst[i]];
    v = v > 0.f ? v : 0.2f * v;
    float e = __expf(v - fdec(mx[dst[i]]));
    atomicAdd(denom + dst[i], e);
    ex_sorted[pos_of_edge[i]] = e;
}

// ---------- GAT: CSR aggregate — wave per node, float4/lane, x4 unroll ----------
// Lane owns cols [lane*4, lane*4+4). 4 independent Hm-row gathers in flight
// per unrolled group (R11 post-mortem: old 1-node-per-block serial loop was
// ~16 dependent L3-latency loads per node).
__global__ void gat_aggregate(const float* __restrict__ Hm, const int* __restrict__ off,
                              const int* __restrict__ srcs_sorted,
                              const float* __restrict__ ex_sorted,
                              const float* __restrict__ denom, const float* __restrict__ bias,
                              float* __restrict__ Gout, int N) {
    int n = blockIdx.x * 4 + (threadIdx.x >> 6);
    int lane = threadIdx.x & 63;
    if (n >= N) return;
    int s0 = off[n], s1 = off[n + 1];
    float4 acc = {0.f, 0.f, 0.f, 0.f};
    int e = s0;
    for (; e + 4 <= s1; e += 4) {
        int sA = srcs_sorted[e],     sB = srcs_sorted[e + 1];
        int sC = srcs_sorted[e + 2], sD = srcs_sorted[e + 3];
        float wA = ex_sorted[e],     wB = ex_sorted[e + 1];
        float wC = ex_sorted[e + 2], wD = ex_sorted[e + 3];
        float4 a = *(const float4*)(Hm + (size_t)sA * 256 + lane * 4);
        float4 b = *(const float4*)(Hm + (size_t)sB * 256 + lane * 4);
        float4 c = *(const float4*)(Hm + (size_t)sC * 256 + lane * 4);
        float4 d = *(const float4*)(Hm + (size_t)sD * 256 + lane * 4);
        acc.x += a.x * wA + b.x * wB + c.x * wC + d.x * wD;
        acc.y += a.y * wA + b.y * wB + c.y * wC + d.y * wD;
        acc.z += a.z * wA + b.z * wB + c.z * wC + d.z * wD;
        acc.w += a.w * wA + b.w * wB + c.w * wC + d.w * wD;
    }
    for (; e < s1; e++) {
        int s = srcs_sorted[e];
        float wgt = ex_sorted[e];
        float4 a = *(const float4*)(Hm + (size_t)s * 256 + lane * 4);
        acc.x += a.x * wgt; acc.y += a.y * wgt; acc.z += a.z * wgt; acc.w += a.w * wgt;
    }
    float inv = (s1 > s0) ? 1.f / denom[n] : 0.f;
    float4 b4 = *(const float4*)(bias + lane * 4);
    float4 o = {acc.x * inv + b4.x, acc.y * inv + b4.y,
                acc.z * inv + b4.z, acc.w * inv + b4.w};
    *(float4*)(Gout + (size_t)n * 256 + lane * 4) = o;
}

// ---------- CSR build ----------
__global__ void zero_int(int* p, int n) {
    int i = blockIdx.x * 256 + threadIdx.x;
    if (i < n) p[i] = 0;
}
__global__ void deg_count(const int* __restrict__ dst, int* __restrict__ deg, int E) {
    int i = blockIdx.x * 256 + threadIdx.x;
    if (i < E) atomicAdd(deg + dst[i], 1);
}
__global__ void scan_k(const int* __restrict__ deg, int* __restrict__ off,
                       int* __restrict__ cursor, int n) {
    __shared__ int buf[256];
    __shared__ int carry_s;
    int tid = threadIdx.x;
    if (tid == 0) carry_s = 0;
    __syncthreads();
    for (int base = 0; base < n; base += 256) {
        int v = (base + tid < n) ? deg[base + tid] : 0;
        buf[tid] = v;
        __syncthreads();
        int x = v;
        for (int s = 1; s < 256; s <<= 1) {
            int tv = (tid >= s) ? buf[tid - s] : 0;
            __syncthreads();
            x += tv; buf[tid] = x;
            __syncthreads();
        }
        int carry = carry_s;
        if (base + tid < n) { off[base + tid] = carry + x - v; cursor[base + tid] = carry + x - v; }
        __syncthreads();
        if (tid == 255) carry_s = carry + x;
        __syncthreads();
    }
    if (tid == 0) off[n] = carry_s;
}
__global__ void scatter_k(const int* __restrict__ src, const int* __restrict__ dst,
                          int* __restrict__ cursor, int* __restrict__ srcs_sorted,
                          int* __restrict__ pos_of_edge, int E) {
    int i = blockIdx.x * 256 + threadIdx.x;
    if (i >= E) return;
    int p = atomicAdd(cursor + dst[i], 1);
    srcs_sorted[p] = src[i];
    pos_of_edge[i] = p;
}

// ---------- launch ----------
extern "C" void kernel_launch(void* const* d_in, const int* in_sizes, int n_in,
                              void* d_out, int out_size, void* d_ws, size_t ws_size,
                              hipStream_t stream) {
    const int N = in_sizes[0] / TT;
    const int E = in_sizes[1] / 2;
    const int EMBN = in_sizes[2];          // V * 128

    const int* X         = (const int*)d_in[0];
    const int* ei        = (const int*)d_in[1];
    const int* srcp      = ei;
    const int* dstp      = ei + E;
    const float* emb     = (const float*)d_in[2];
    const float* Wih_f   = (const float*)d_in[3];
    const float* Whh_f   = (const float*)d_in[4];
    const float* bih_f   = (const float*)d_in[5];
    const float* bhh_f   = (const float*)d_in[6];
    const float* Wih_b   = (const float*)d_in[7];
    const float* Whh_b   = (const float*)d_in[8];
    const float* bih_b   = (const float*)d_in[9];
    const float* bhh_b   = (const float*)d_in[10];
    const float* Wg      = (const float*)d_in[11];
    const float* att_src = (const float*)d_in[12];
    const float* att_dst = (const float*)d_in[13];
    const float* bg      = (const float*)d_in[14];

    float* out     = (float*)d_out;
    float* g_final = out;
    float* qn      = out + (size_t)N * 256;
    float* q       = out + (size_t)2 * N * 256;

    // ws layout
    float* w = (float*)d_ws;
    unsigned short* Whi_f = (unsigned short*)w; w += 49152;  // 384*256 ushort
    unsigned short* Wlo_f = (unsigned short*)w; w += 49152;
    unsigned short* Whi_b = (unsigned short*)w; w += 49152;
    unsigned short* Wlo_b = (unsigned short*)w; w += 49152;
    unsigned short* Wghi  = (unsigned short*)w; w += 32768;  // 256*256 ushort
    unsigned short* Wglo  = (unsigned short*)w; w += 32768;
    unsigned short* ehi   = (unsigned short*)w; w += (EMBN + 1) / 2;
    unsigned short* elo   = (unsigned short*)w; w += (EMBN + 1) / 2;
    float* bufA  = w; w += (size_t)N * 256;
    float* bufB  = w; w += (size_t)N * 256;
    float* Hbuf  = w; w += (size_t)N * 256;
    float* a_src = w; w += N;
    float* a_dst = w; w += N;
    float* denom = w; w += N;
    unsigned* mx = (unsigned*)w; w += N;
    float* ex_sorted = w; w += E;
    int* iw = (int*)w;
    int* deg         = iw; iw += N;
    int* cursor      = iw; iw += N;
    int* off         = iw; iw += N + 1;
    int* srcs_sorted = iw; iw += E;
    int* pos_of_edge = iw; iw += E;

    // 1. weight + emb plane prep
    prep_w<<<384, 256, 0, stream>>>(Wih_f, Whh_f, Wih_b, Whh_b, Wg,
                                    Whi_f, Wlo_f, Whi_b, Wlo_b, Wghi, Wglo);
    prep_emb<<<(EMBN + 255) / 256, 256, 0, stream>>>(emb, ehi, elo, EMBN);
    // 2. fused biGRU (R5/R8 config), writes q and q_n
    dim3 ggrid((N + NB - 1) / NB, 2);
    gru_kernel<<<ggrid, 512, 0, stream>>>(X, ehi, elo, Whi_f, Wlo_f, Whi_b, Wlo_b,
                                          bih_f, bhh_f, bih_b, bhh_b, q, qn, N);
    // 3. CSR build (once, reused by all 4 layers)
    zero_int<<<(N + 255) / 256, 256, 0, stream>>>(deg, N);
    deg_count<<<(E + 255) / 256, 256, 0, stream>>>(dstp, deg, E);
    scan_k<<<1, 256, 0, stream>>>(deg, off, cursor, N);
    scatter_k<<<(E + 255) / 256, 256, 0, stream>>>(srcp, dstp, cursor, srcs_sorted,
                                                   pos_of_edge, E);
    // 4. 4 GAT layers (shared weights)
    const float* gin = qn;
    float* gouts[4] = {bufA, bufB, bufA, g_final};
    for (int l = 0; l < 4; l++) {
        gat_matmul<<<(N + 31) / 32, 256, 0, stream>>>(gin, Wghi, Wglo, Hbuf, N);
        gat_dots<<<(N + 3) / 4, 256, 0, stream>>>(Hbuf, att_src, att_dst, a_src, a_dst,
                                                  mx, denom, N);
        edge_max<<<(E + 255) / 256, 256, 0, stream>>>(srcp, dstp, a_src, a_dst, mx, E);
        edge_exp<<<(E + 255) / 256, 256, 0, stream>>>(srcp, dstp, a_src, a_dst, mx, denom,
                                                      pos_of_edge, ex_sorted, E);
        gat_aggregate<<<(N + 3) / 4, 256, 0, stream>>>(Hbuf, off, srcs_sorted, ex_sorted,
                                                       denom, bg, gouts[l], N);
        gin = gouts[l];
    }
}

// Round 13
// 1491.309 us; speedup vs baseline: 4.1756x; 1.2138x over previous
//
#include <hip/hip_runtime.h>

#define TT 32
#define NB 16   // nodes per GRU block

typedef __attribute__((ext_vector_type(8))) short short8;
typedef __attribute__((ext_vector_type(4))) float f32x4;

// ---------- helpers ----------
__device__ __host__ inline unsigned short f2bf(float f) {
    unsigned u = __float_as_uint(f);
    return (unsigned short)((u + 0x7FFFu + ((u >> 16) & 1u)) >> 16);
}
__device__ inline float bf2f(unsigned short h) {
    return __uint_as_float(((unsigned)h) << 16);
}
__device__ inline unsigned fenc(float f) {
    unsigned b = __float_as_uint(f);
    return (b & 0x80000000u) ? ~b : (b | 0x80000000u);
}
__device__ inline float fdec(unsigned u) {
    unsigned b = (u & 0x80000000u) ? (u & 0x7FFFFFFFu) : ~u;
    return __uint_as_float(b);
}
#define ENC_NEG_INF 0x007FFFFFu   // fenc(-inf)

// ---------- weight prep ----------
// GRU: W planes [384 col][256 k] bf16 hi/lo per dir. GAT: Wg planes
// [256 col][256 k] bf16 hi/lo (B[col][k] = Wg[col*256+k], no transpose).
__global__ void prep_w(const float* __restrict__ Wih_f, const float* __restrict__ Whh_f,
                       const float* __restrict__ Wih_b, const float* __restrict__ Whh_b,
                       const float* __restrict__ Wg,
                       unsigned short* __restrict__ Whi_f, unsigned short* __restrict__ Wlo_f,
                       unsigned short* __restrict__ Whi_b, unsigned short* __restrict__ Wlo_b,
                       unsigned short* __restrict__ Wghi, unsigned short* __restrict__ Wglo) {
    int i = blockIdx.x * 256 + threadIdx.x;
    if (i < 384 * 256) {
        int col = i / 256, k = i % 256;
        float ff = (k < 128) ? Wih_f[col * 128 + k] : Whh_f[col * 128 + (k - 128)];
        float fb = (k < 128) ? Wih_b[col * 128 + k] : Whh_b[col * 128 + (k - 128)];
        unsigned short hf = f2bf(ff);
        Whi_f[i] = hf; Wlo_f[i] = f2bf(ff - bf2f(hf));
        unsigned short hb = f2bf(fb);
        Whi_b[i] = hb; Wlo_b[i] = f2bf(fb - bf2f(hb));
    }
    if (i < 256 * 256) {
        float g = Wg[i];
        unsigned short h = f2bf(g);
        Wghi[i] = h; Wglo[i] = f2bf(g - bf2f(h));
    }
}

// ---------- emb bf16 hi/lo plane prep ----------
__global__ void prep_emb(const float* __restrict__ emb, unsigned short* __restrict__ ehi,
                         unsigned short* __restrict__ elo, int n) {
    int i = blockIdx.x * 256 + threadIdx.x;
    if (i < n) {
        float e = emb[i];
        unsigned short h = f2bf(e);
        ehi[i] = h; elo[i] = f2bf(e - bf2f(h));
    }
}

// ---------- fused biGRU: R8 config verbatim (best measured: 1017-1020 us) ----------
// 512 threads = 8 waves, 16 nodes/block, dbuf LDS. B-fragments loaded via
// arrays before the t-loop — the compiler remats them into the loop AS A
// BATCHED LOAD CLUSTER that pipelines well (R12 post-mortem: hand-inlined
// per-kc loads serialize against MFMAs, FETCH 2x, -330us). Keep array form.
#define PIN(x) asm volatile("" : "+v"(x))
__global__ __launch_bounds__(512)
__attribute__((amdgpu_waves_per_eu(2, 2)))
void gru_kernel(const int* __restrict__ X,
                const unsigned short* __restrict__ ehi, const unsigned short* __restrict__ elo,
                const unsigned short* __restrict__ Whi_f, const unsigned short* __restrict__ Wlo_f,
                const unsigned short* __restrict__ Whi_b, const unsigned short* __restrict__ Wlo_b,
                const float* __restrict__ bih_f, const float* __restrict__ bhh_f,
                const float* __restrict__ bih_b, const float* __restrict__ bhh_b,
                float* __restrict__ q_out, float* __restrict__ qn_out, int N) {
    const int dir  = blockIdx.y;
    const int base = blockIdx.x * NB;
    const int tid  = threadIdx.x;
    const int lane = tid & 63;
    const int w    = tid >> 6;      // wave 0..7
    const int l15  = lane & 15;
    const int l4   = lane >> 4;     // 0..3

    const unsigned short* __restrict__ Whi = dir ? Whi_b : Whi_f;
    const unsigned short* __restrict__ Wlo = dir ? Wlo_b : Wlo_f;
    const float* __restrict__ bih = dir ? bih_b : bih_f;
    const float* __restrict__ bhh = dir ? bhh_b : bhh_f;

    __shared__ __align__(16) char smem[32768];   // 2 buffers x (Ahi 8K + Alo 8K)

    const int j = w * 16 + l15;        // owned output col (per gate)
    const float bR  = bih[j]       + bhh[j];
    const float bZ  = bih[j + 128] + bhh[j + 128];
    const float bXN = bih[j + 256];
    const float bHN = bhh[j + 256];

    // ---- load B fragments into registers (once) and PIN them ----
    short8 bh[3][8], bl[3][8];
    #pragma unroll
    for (int g = 0; g < 3; g++)
        #pragma unroll
        for (int kc = 0; kc < 8; kc++) {
            int off = (g * 128 + j) * 256 + kc * 32 + l4 * 8;
            bh[g][kc] = *(const short8*)(Whi + off);
            bl[g][kc] = *(const short8*)(Wlo + off);
            PIN(bh[g][kc]);
            PIN(bl[g][kc]);
        }

    // A-frag read base: row = l15, kbyte = kc*64 + l4*16
    const int amask = (l15 & 7) << 4;
    const int abase = l15 * 512 + l4 * 16;

    // zero h-region of buffer 0 (rows 0..15, bytes 256..511, both planes)
    for (int i = tid; i < 2048; i += 512) {
        int plane = i >> 10, idx = i & 1023;
        int row = idx >> 6, d = idx & 63;
        *(unsigned*)(smem + plane * 8192 + row * 512 + 256 + d * 4) = 0u;
    }

    // staging: thread -> (node snode, 4 k at sk); pure 8B+8B copy
    const int snode = tid >> 5;
    const int sk    = (tid & 31) * 4;
    const int sb    = (snode * 512 + sk * 2) ^ ((snode & 7) << 4);
    int node_s = base + snode; if (node_s >= N) node_s = N - 1;
    const int* Xrow = X + (size_t)node_s * TT;
    auto teff = [&](int t) { return dir ? (TT - 1 - t) : t; };

    { // stage x(0) into buffer 0
        int idx0 = Xrow[teff(0)];
        *(ushort4*)(smem + sb)        = *(const ushort4*)(ehi + (size_t)idx0 * 128 + sk);
        *(ushort4*)(smem + 8192 + sb) = *(const ushort4*)(elo + (size_t)idx0 * 128 + sk);
    }
    int idxA = Xrow[teff(1)];    // index for x(1), prefetched

    float hprev[4] = {0.f, 0.f, 0.f, 0.f};
    const int jd = j & ~1;       // even col of the (j, j^1) pair

    for (int t = 0; t < TT; t++) {
        __syncthreads();   // buf[cur] (x_t + h_t) fully written

        char* pA = smem + (t & 1) * 16384;        // current buffer
        char* pN = smem + ((t + 1) & 1) * 16384;  // next buffer

        // issue next-step staging loads (latency hidden under MFMA)
        ushort4 uhi, ulo;
        if (t < TT - 1) {
            uhi = *(const ushort4*)(ehi + (size_t)idxA * 128 + sk);
            ulo = *(const ushort4*)(elo + (size_t)idxA * 128 + sk);
            if (t < TT - 2) idxA = Xrow[teff(t + 2)];
        }

        f32x4 aR  = (f32x4){0.f, 0.f, 0.f, 0.f};
        f32x4 aZ  = (f32x4){0.f, 0.f, 0.f, 0.f};
        f32x4 aNX = (f32x4){0.f, 0.f, 0.f, 0.f};
        f32x4 aNH = (f32x4){0.f, 0.f, 0.f, 0.f};
        #pragma unroll
        for (int kc = 0; kc < 8; kc++) {
            int ao = (abase + kc * 64) ^ amask;
            short8 ah = *(const short8*)(pA + ao);
            short8 al = *(const short8*)(pA + 8192 + ao);
            f32x4& an = (kc < 4) ? aNX : aNH;
            aR = __builtin_amdgcn_mfma_f32_16x16x32_bf16(ah, bh[0][kc], aR, 0, 0, 0);
            aZ = __builtin_amdgcn_mfma_f32_16x16x32_bf16(ah, bh[1][kc], aZ, 0, 0, 0);
            an = __builtin_amdgcn_mfma_f32_16x16x32_bf16(ah, bh[2][kc], an, 0, 0, 0);
            aR = __builtin_amdgcn_mfma_f32_16x16x32_bf16(al, bh[0][kc], aR, 0, 0, 0);
            aZ = __builtin_amdgcn_mfma_f32_16x16x32_bf16(al, bh[1][kc], aZ, 0, 0, 0);
            an = __builtin_amdgcn_mfma_f32_16x16x32_bf16(al, bh[2][kc], an, 0, 0, 0);
            aR = __builtin_amdgcn_mfma_f32_16x16x32_bf16(ah, bl[0][kc], aR, 0, 0, 0);
            aZ = __builtin_amdgcn_mfma_f32_16x16x32_bf16(ah, bl[1][kc], aZ, 0, 0, 0);
            an = __builtin_amdgcn_mfma_f32_16x16x32_bf16(ah, bl[2][kc], an, 0, 0, 0);
        }

        // gates + h carry; h(t+1) goes to NEXT buffer (packed b32 writes)
        #pragma unroll
        for (int rr = 0; rr < 4; rr++) {
            int nl = l4 * 4 + rr;      // local node (C/D row map)
            float r = 1.f / (1.f + __expf(-(aR[rr] + bR)));
            float z = 1.f / (1.f + __expf(-(aZ[rr] + bZ)));
            float p = aNX[rr] + bXN + r * (aNH[rr] + bHN);
            float n = 1.f - 2.f / (__expf(2.f * p) + 1.f);   // tanh, overflow-safe
            float h = (1.f - z) * n + z * hprev[rr];
            hprev[rr] = h;
            unsigned short hh = f2bf(h);
            unsigned short ll = f2bf(h - bf2f(hh));
            unsigned pk = (unsigned)hh | ((unsigned)ll << 16);
            unsigned pp = __shfl_xor(pk, 1);
            if ((l15 & 1) == 0) {      // even lane writes the (j, j+1) pair
                unsigned hiw = (pk & 0xFFFFu) | (pp << 16);
                unsigned low = (pk >> 16) | (pp & 0xFFFF0000u);
                int hb = (nl * 512 + 256 + 2 * jd) ^ ((nl & 7) << 4);
                *(unsigned*)(pN + hb) = hiw;
                *(unsigned*)(pN + 8192 + hb) = low;
            }
            int node = base + nl;
            if (node < N) {
                q_out[((size_t)t * N + node) * 256 + dir * 128 + j] = h;
                if (t == TT - 1)
                    qn_out[(size_t)node * 256 + dir * 128 + j] = h;
            }
        }
        // write staged x(t+1) into next buffer
        if (t < TT - 1) {
            *(ushort4*)(pN + sb)        = uhi;
            *(ushort4*)(pN + 8192 + sb) = ulo;
        }
    }
}

// ---------- GAT: h = g @ Wg.T via bf16 MFMA 3-pass ----------
// 256 threads = 4 waves, 32 nodes/block (2 M-tiles). Wave w owns cols
// [64w, 64w+64) = 4 col-tiles of 16. A staged fp32->bf16 hi/lo in LDS
// (same XOR swizzle as GRU, verified). B streamed from L2 (128KB planes).
__global__ __launch_bounds__(256)
void gat_matmul(const float* __restrict__ G,
                const unsigned short* __restrict__ Wghi, const unsigned short* __restrict__ Wglo,
                float* __restrict__ Hout, int N) {
    const int base = blockIdx.x * 32;
    const int tid  = threadIdx.x;
    const int lane = tid & 63;
    const int w    = tid >> 6;      // wave 0..3
    const int l15  = lane & 15;
    const int l4   = lane >> 4;

    __shared__ __align__(16) char smem[32768];   // hi @0, lo @16384

    // staging: snode = tid>>3 (0..31), sk = (tid&7)*32 (k per thread: 32)
    const int snode = tid >> 3;
    const int sk    = (tid & 7) * 32;
    const int smask = (snode & 7) << 4;
    int node_s = base + snode; if (node_s >= N) node_s = N - 1;
    const float* gr = G + (size_t)node_s * 256 + sk;
    #pragma unroll
    for (int c = 0; c < 4; c++) {
        float4 v0 = *(const float4*)(gr + c * 8);
        float4 v1 = *(const float4*)(gr + c * 8 + 4);
        unsigned short h0 = f2bf(v0.x), h1 = f2bf(v0.y), h2 = f2bf(v0.z), h3 = f2bf(v0.w);
        unsigned short h4 = f2bf(v1.x), h5 = f2bf(v1.y), h6 = f2bf(v1.z), h7 = f2bf(v1.w);
        uint4 hi = {(unsigned)h0 | ((unsigned)h1 << 16), (unsigned)h2 | ((unsigned)h3 << 16),
                    (unsigned)h4 | ((unsigned)h5 << 16), (unsigned)h6 | ((unsigned)h7 << 16)};
        uint4 lo = {(unsigned)f2bf(v0.x - bf2f(h0)) | ((unsigned)f2bf(v0.y - bf2f(h1)) << 16),
                    (unsigned)f2bf(v0.z - bf2f(h2)) | ((unsigned)f2bf(v0.w - bf2f(h3)) << 16),
                    (unsigned)f2bf(v1.x - bf2f(h4)) | ((unsigned)f2bf(v1.y - bf2f(h5)) << 16),
                    (unsigned)f2bf(v1.z - bf2f(h6)) | ((unsigned)f2bf(v1.w - bf2f(h7)) << 16)};
        int addr = (snode * 512 + (sk + c * 8) * 2) ^ smask;
        *(uint4*)(smem + addr) = hi;
        *(uint4*)(smem + 16384 + addr) = lo;
    }
    __syncthreads();

    // A-frag bases for 2 M-tiles
    int aob[2], amask[2];
    #pragma unroll
    for (int mt = 0; mt < 2; mt++) {
        int row = mt * 16 + l15;
        aob[mt]   = row * 512 + l4 * 16;
        amask[mt] = (row & 7) << 4;
    }
    // B-frag bases for 4 col-tiles
    int bb[4];
    #pragma unroll
    for (int th = 0; th < 4; th++)
        bb[th] = (w * 64 + th * 16 + l15) * 256 + l4 * 8;

    f32x4 acc[4][2];
    #pragma unroll
    for (int th = 0; th < 4; th++)
        #pragma unroll
        for (int mt = 0; mt < 2; mt++) acc[th][mt] = (f32x4){0.f, 0.f, 0.f, 0.f};

    #pragma unroll
    for (int kc = 0; kc < 8; kc++) {
        short8 ah[2], al[2];
        #pragma unroll
        for (int mt = 0; mt < 2; mt++) {
            int ao = (aob[mt] + kc * 64) ^ amask[mt];
            ah[mt] = *(const short8*)(smem + ao);
            al[mt] = *(const short8*)(smem + 16384 + ao);
        }
        #pragma unroll
        for (int th = 0; th < 4; th++) {
            int bo = bb[th] + kc * 32;
            short8 bh = *(const short8*)(Wghi + bo);
            short8 bl = *(const short8*)(Wglo + bo);
            #pragma unroll
            for (int mt = 0; mt < 2; mt++) {
                acc[th][mt] = __builtin_amdgcn_mfma_f32_16x16x32_bf16(ah[mt], bh, acc[th][mt], 0, 0, 0);
                acc[th][mt] = __builtin_amdgcn_mfma_f32_16x16x32_bf16(al[mt], bh, acc[th][mt], 0, 0, 0);
                acc[th][mt] = __builtin_amdgcn_mfma_f32_16x16x32_bf16(ah[mt], bl, acc[th][mt], 0, 0, 0);
            }
        }
    }

    #pragma unroll
    for (int th = 0; th < 4; th++)
        #pragma unroll
        for (int mt = 0; mt < 2; mt++)
            #pragma unroll
            for (int rr = 0; rr < 4; rr++) {
                int node = base + mt * 16 + l4 * 4 + rr;
                int col  = w * 64 + th * 16 + l15;
                if (node < N) Hout[(size_t)node * 256 + col] = acc[th][mt][rr];
            }
}

// ---------- GAT: attention dots + per-node init ----------
__global__ void gat_dots(const float* __restrict__ Hm, const float* __restrict__ att_src,
                         const float* __restrict__ att_dst, float* __restrict__ a_src,
                         float* __restrict__ a_dst, unsigned* __restrict__ mx,
                         float* __restrict__ denom, int N) {
    int node = blockIdx.x * 4 + (threadIdx.x >> 6);
    int lane = threadIdx.x & 63;
    if (node >= N) return;
    const float* hr = Hm + (size_t)node * 256;
    float s1 = 0.f, s2 = 0.f;
    #pragma unroll
    for (int c = 0; c < 4; c++) {
        float h = hr[lane + 64 * c];
        s1 += h * att_src[lane + 64 * c];
        s2 += h * att_dst[lane + 64 * c];
    }
    #pragma unroll
    for (int o = 32; o > 0; o >>= 1) { s1 += __shfl_down(s1, o); s2 += __shfl_down(s2, o); }
    if (lane == 0) {
        a_src[node] = s1; a_dst[node] = s2;
        mx[node] = ENC_NEG_INF; denom[node] = 0.f;
    }
}

__global__ void edge_max(const int* __restrict__ src, const int* __restrict__ dst,
                         const float* __restrict__ a_src, const float* __restrict__ a_dst,
                         unsigned* __restrict__ mx, int E) {
    int i = blockIdx.x * 256 + threadIdx.x;
    if (i >= E) return;
    float v = a_src[src[i]] + a_dst[dst[i]];
    v = v > 0.f ? v : 0.2f * v;
    atomicMax(mx + dst[i], fenc(v));
}

__global__ void edge_exp(const int* __restrict__ src, const int* __restrict__ dst,
                         const float* __restrict__ a_src, const float* __restrict__ a_dst,
                         const unsigned* __restrict__ mx, float* __restrict__ denom,
                         const int* __restrict__ pos_of_edge, float* __restrict__ ex_sorted,
                         int E) {
    int i = blockIdx.x * 256 + threadIdx.x;
    if (i >= E) return;
    float v = a_src[src[i]] + a_dst[dst[i]];
    v = v > 0.f ? v : 0.2f * v;
    float e = __expf(v - fdec(mx[dst[i]]));
    atomicAdd(denom + dst[i], e);
    ex_sorted[pos_of_edge[i]] = e;
}

// ---------- GAT: CSR aggregate — wave per node, float4/lane, x4 unroll ----------
__global__ void gat_aggregate(const float* __restrict__ Hm, const int* __restrict__ off,
                              const int* __restrict__ srcs_sorted,
                              const float* __restrict__ ex_sorted,
                              const float* __restrict__ denom, const float* __restrict__ bias,
                              float* __restrict__ Gout, int N) {
    int n = blockIdx.x * 4 + (threadIdx.x >> 6);
    int lane = threadIdx.x & 63;
    if (n >= N) return;
    int s0 = off[n], s1 = off[n + 1];
    float4 acc = {0.f, 0.f, 0.f, 0.f};
    int e = s0;
    for (; e + 4 <= s1; e += 4) {
        int sA = srcs_sorted[e],     sB = srcs_sorted[e + 1];
        int sC = srcs_sorted[e + 2], sD = srcs_sorted[e + 3];
        float wA = ex_sorted[e],     wB = ex_sorted[e + 1];
        float wC = ex_sorted[e + 2], wD = ex_sorted[e + 3];
        float4 a = *(const float4*)(Hm + (size_t)sA * 256 + lane * 4);
        float4 b = *(const float4*)(Hm + (size_t)sB * 256 + lane * 4);
        float4 c = *(const float4*)(Hm + (size_t)sC * 256 + lane * 4);
        float4 d = *(const float4*)(Hm + (size_t)sD * 256 + lane * 4);
        acc.x += a.x * wA + b.x * wB + c.x * wC + d.x * wD;
        acc.y += a.y * wA + b.y * wB + c.y * wC + d.y * wD;
        acc.z += a.z * wA + b.z * wB + c.z * wC + d.z * wD;
        acc.w += a.w * wA + b.w * wB + c.w * wC + d.w * wD;
    }
    for (; e < s1; e++) {
        int s = srcs_sorted[e];
        float wgt = ex_sorted[e];
        float4 a = *(const float4*)(Hm + (size_t)s * 256 + lane * 4);
        acc.x += a.x * wgt; acc.y += a.y * wgt; acc.z += a.z * wgt; acc.w += a.w * wgt;
    }
    float inv = (s1 > s0) ? 1.f / denom[n] : 0.f;
    float4 b4 = *(const float4*)(bias + lane * 4);
    float4 o = {acc.x * inv + b4.x, acc.y * inv + b4.y,
                acc.z * inv + b4.z, acc.w * inv + b4.w};
    *(float4*)(Gout + (size_t)n * 256 + lane * 4) = o;
}

// ---------- CSR build ----------
__global__ void zero_int(int* p, int n) {
    int i = blockIdx.x * 256 + threadIdx.x;
    if (i < n) p[i] = 0;
}
__global__ void deg_count(const int* __restrict__ dst, int* __restrict__ deg, int E) {
    int i = blockIdx.x * 256 + threadIdx.x;
    if (i < E) atomicAdd(deg + dst[i], 1);
}
__global__ void scan_k(const int* __restrict__ deg, int* __restrict__ off,
                       int* __restrict__ cursor, int n) {
    __shared__ int buf[256];
    __shared__ int carry_s;
    int tid = threadIdx.x;
    if (tid == 0) carry_s = 0;
    __syncthreads();
    for (int base = 0; base < n; base += 256) {
        int v = (base + tid < n) ? deg[base + tid] : 0;
        buf[tid] = v;
        __syncthreads();
        int x = v;
        for (int s = 1; s < 256; s <<= 1) {
            int tv = (tid >= s) ? buf[tid - s] : 0;
            __syncthreads();
            x += tv; buf[tid] = x;
            __syncthreads();
        }
        int carry = carry_s;
        if (base + tid < n) { off[base + tid] = carry + x - v; cursor[base + tid] = carry + x - v; }
        __syncthreads();
        if (tid == 255) carry_s = carry + x;
        __syncthreads();
    }
    if (tid == 0) off[n] = carry_s;
}
__global__ void scatter_k(const int* __restrict__ src, const int* __restrict__ dst,
                          int* __restrict__ cursor, int* __restrict__ srcs_sorted,
                          int* __restrict__ pos_of_edge, int E) {
    int i = blockIdx.x * 256 + threadIdx.x;
    if (i >= E) return;
    int p = atomicAdd(cursor + dst[i], 1);
    srcs_sorted[p] = src[i];
    pos_of_edge[i] = p;
}

// ---------- launch ----------
extern "C" void kernel_launch(void* const* d_in, const int* in_sizes, int n_in,
                              void* d_out, int out_size, void* d_ws, size_t ws_size,
                              hipStream_t stream) {
    const int N = in_sizes[0] / TT;
    const int E = in_sizes[1] / 2;
    const int EMBN = in_sizes[2];          // V * 128

    const int* X         = (const int*)d_in[0];
    const int* ei        = (const int*)d_in[1];
    const int* srcp      = ei;
    const int* dstp      = ei + E;
    const float* emb     = (const float*)d_in[2];
    const float* Wih_f   = (const float*)d_in[3];
    const float* Whh_f   = (const float*)d_in[4];
    const float* bih_f   = (const float*)d_in[5];
    const float* bhh_f   = (const float*)d_in[6];
    const float* Wih_b   = (const float*)d_in[7];
    const float* Whh_b   = (const float*)d_in[8];
    const float* bih_b   = (const float*)d_in[9];
    const float* bhh_b   = (const float*)d_in[10];
    const float* Wg      = (const float*)d_in[11];
    const float* att_src = (const float*)d_in[12];
    const float* att_dst = (const float*)d_in[13];
    const float* bg      = (const float*)d_in[14];

    float* out     = (float*)d_out;
    float* g_final = out;
    float* qn      = out + (size_t)N * 256;
    float* q       = out + (size_t)2 * N * 256;

    // ws layout
    float* w = (float*)d_ws;
    unsigned short* Whi_f = (unsigned short*)w; w += 49152;  // 384*256 ushort
    unsigned short* Wlo_f = (unsigned short*)w; w += 49152;
    unsigned short* Whi_b = (unsigned short*)w; w += 49152;
    unsigned short* Wlo_b = (unsigned short*)w; w += 49152;
    unsigned short* Wghi  = (unsigned short*)w; w += 32768;  // 256*256 ushort
    unsigned short* Wglo  = (unsigned short*)w; w += 32768;
    unsigned short* ehi   = (unsigned short*)w; w += (EMBN + 1) / 2;
    unsigned short* elo   = (unsigned short*)w; w += (EMBN + 1) / 2;
    float* bufA  = w; w += (size_t)N * 256;
    float* bufB  = w; w += (size_t)N * 256;
    float* Hbuf  = w; w += (size_t)N * 256;
    float* a_src = w; w += N;
    float* a_dst = w; w += N;
    float* denom = w; w += N;
    unsigned* mx = (unsigned*)w; w += N;
    float* ex_sorted = w; w += E;
    int* iw = (int*)w;
    int* deg         = iw; iw += N;
    int* cursor      = iw; iw += N;
    int* off         = iw; iw += N + 1;
    int* srcs_sorted = iw; iw += E;
    int* pos_of_edge = iw; iw += E;

    // 1. weight + emb plane prep
    prep_w<<<384, 256, 0, stream>>>(Wih_f, Whh_f, Wih_b, Whh_b, Wg,
                                    Whi_f, Wlo_f, Whi_b, Wlo_b, Wghi, Wglo);
    prep_emb<<<(EMBN + 255) / 256, 256, 0, stream>>>(emb, ehi, elo, EMBN);
    // 2. fused biGRU (R8 config), writes q and q_n
    dim3 ggrid((N + NB - 1) / NB, 2);
    gru_kernel<<<ggrid, 512, 0, stream>>>(X, ehi, elo, Whi_f, Wlo_f, Whi_b, Wlo_b,
                                          bih_f, bhh_f, bih_b, bhh_b, q, qn, N);
    // 3. CSR build (once, reused by all 4 layers)
    zero_int<<<(N + 255) / 256, 256, 0, stream>>>(deg, N);
    deg_count<<<(E + 255) / 256, 256, 0, stream>>>(dstp, deg, E);
    scan_k<<<1, 256, 0, stream>>>(deg, off, cursor, N);
    scatter_k<<<(E + 255) / 256, 256, 0, stream>>>(srcp, dstp, cursor, srcs_sorted,
                                                   pos_of_edge, E);
    // 4. 4 GAT layers (shared weights)
    const float* gin = qn;
    float* gouts[4] = {bufA, bufB, bufA, g_final};
    for (int l = 0; l < 4; l++) {
        gat_matmul<<<(N + 31) / 32, 256, 0, stream>>>(gin, Wghi, Wglo, Hbuf, N);
        gat_dots<<<(N + 3) / 4, 256, 0, stream>>>(Hbuf, att_src, att_dst, a_src, a_dst,
                                                  mx, denom, N);
        edge_max<<<(E + 255) / 256, 256, 0, stream>>>(srcp, dstp, a_src, a_dst, mx, E);
        edge_exp<<<(E + 255) / 256, 256, 0, stream>>>(srcp, dstp, a_src, a_dst, mx, denom,
                                                      pos_of_edge, ex_sorted, E);
        gat_aggregate<<<(N + 3) / 4, 256, 0, stream>>>(Hbuf, off, srcs_sorted, ex_sorted,
                                                       denom, bg, gouts[l], N);
        gin = gouts[l];
    }
}

// Round 14
// 1290.008 us; speedup vs baseline: 4.8272x; 1.1560x over previous
//
#include <hip/hip_runtime.h>

#define TT 32
#define NB 16   // nodes per GRU block

typedef __attribute__((ext_vector_type(8))) short short8;
typedef __attribute__((ext_vector_type(4))) float f32x4;

// ---------- helpers ----------
__device__ __host__ inline unsigned short f2bf(float f) {
    unsigned u = __float_as_uint(f);
    return (unsigned short)((u + 0x7FFFu + ((u >> 16) & 1u)) >> 16);
}
__device__ inline float bf2f(unsigned short h) {
    return __uint_as_float(((unsigned)h) << 16);
}
__device__ inline unsigned fenc(float f) {
    unsigned b = __float_as_uint(f);
    return (b & 0x80000000u) ? ~b : (b | 0x80000000u);
}
__device__ inline float fdec(unsigned u) {
    unsigned b = (u & 0x80000000u) ? (u & 0x7FFFFFFFu) : ~u;
    return __uint_as_float(b);
}
#define ENC_NEG_INF 0x007FFFFFu   // fenc(-inf)

// ---------- weight prep ----------
// GRU: W planes [384 col][256 k] bf16 hi (lo dropped — 2-pass, R14). GAT: Wg
// planes [256 col][256 k] bf16 hi/lo (3-pass kept).
__global__ void prep_w(const float* __restrict__ Wih_f, const float* __restrict__ Whh_f,
                       const float* __restrict__ Wih_b, const float* __restrict__ Whh_b,
                       const float* __restrict__ Wg,
                       unsigned short* __restrict__ Whi_f,
                       unsigned short* __restrict__ Whi_b,
                       unsigned short* __restrict__ Wghi, unsigned short* __restrict__ Wglo) {
    int i = blockIdx.x * 256 + threadIdx.x;
    if (i < 384 * 256) {
        int col = i / 256, k = i % 256;
        float ff = (k < 128) ? Wih_f[col * 128 + k] : Whh_f[col * 128 + (k - 128)];
        float fb = (k < 128) ? Wih_b[col * 128 + k] : Whh_b[col * 128 + (k - 128)];
        Whi_f[i] = f2bf(ff);
        Whi_b[i] = f2bf(fb);
    }
    if (i < 256 * 256) {
        float g = Wg[i];
        unsigned short h = f2bf(g);
        Wghi[i] = h; Wglo[i] = f2bf(g - bf2f(h));
    }
}

// ---------- emb bf16 hi/lo plane prep ----------
__global__ void prep_emb(const float* __restrict__ emb, unsigned short* __restrict__ ehi,
                         unsigned short* __restrict__ elo, int n) {
    int i = blockIdx.x * 256 + threadIdx.x;
    if (i < n) {
        float e = emb[i];
        unsigned short h = f2bf(e);
        ehi[i] = h; elo[i] = f2bf(e - bf2f(h));
    }
}

// ---------- fused biGRU: R8 structure, 2-pass (W bf16-hi only) ----------
// 512 threads = 8 waves, 16 nodes/block, dbuf LDS. A = x,h kept hi+lo (split
// recurrent state stays ~fp32); W quantized to bf16 — dropping Ah*Bl halves
// B-loads/step 48->24 and MFMAs 72->48 (R13 post-mortem: step time = serial
// B-load chain, 48 x ~165cy). Array-form B loads + PIN kept (R12 lesson).
#define PIN(x) asm volatile("" : "+v"(x))
__global__ __launch_bounds__(512)
__attribute__((amdgpu_waves_per_eu(2, 2)))
void gru_kernel(const int* __restrict__ X,
                const unsigned short* __restrict__ ehi, const unsigned short* __restrict__ elo,
                const unsigned short* __restrict__ Whi_f,
                const unsigned short* __restrict__ Whi_b,
                const float* __restrict__ bih_f, const float* __restrict__ bhh_f,
                const float* __restrict__ bih_b, const float* __restrict__ bhh_b,
                float* __restrict__ q_out, float* __restrict__ qn_out, int N) {
    const int dir  = blockIdx.y;
    const int base = blockIdx.x * NB;
    const int tid  = threadIdx.x;
    const int lane = tid & 63;
    const int w    = tid >> 6;      // wave 0..7
    const int l15  = lane & 15;
    const int l4   = lane >> 4;     // 0..3

    const unsigned short* __restrict__ Whi = dir ? Whi_b : Whi_f;
    const float* __restrict__ bih = dir ? bih_b : bih_f;
    const float* __restrict__ bhh = dir ? bhh_b : bhh_f;

    __shared__ __align__(16) char smem[32768];   // 2 buffers x (Ahi 8K + Alo 8K)

    const int j = w * 16 + l15;        // owned output col (per gate)
    const float bR  = bih[j]       + bhh[j];
    const float bZ  = bih[j + 128] + bhh[j + 128];
    const float bXN = bih[j + 256];
    const float bHN = bhh[j + 256];

    // ---- load B fragments into registers (once) and PIN them ----
    short8 bh[3][8];
    #pragma unroll
    for (int g = 0; g < 3; g++)
        #pragma unroll
        for (int kc = 0; kc < 8; kc++) {
            int off = (g * 128 + j) * 256 + kc * 32 + l4 * 8;
            bh[g][kc] = *(const short8*)(Whi + off);
            PIN(bh[g][kc]);
        }

    // A-frag read base: row = l15, kbyte = kc*64 + l4*16
    const int amask = (l15 & 7) << 4;
    const int abase = l15 * 512 + l4 * 16;

    // zero h-region of buffer 0 (rows 0..15, bytes 256..511, both planes)
    for (int i = tid; i < 2048; i += 512) {
        int plane = i >> 10, idx = i & 1023;
        int row = idx >> 6, d = idx & 63;
        *(unsigned*)(smem + plane * 8192 + row * 512 + 256 + d * 4) = 0u;
    }

    // staging: thread -> (node snode, 4 k at sk); pure 8B+8B copy
    const int snode = tid >> 5;
    const int sk    = (tid & 31) * 4;
    const int sb    = (snode * 512 + sk * 2) ^ ((snode & 7) << 4);
    int node_s = base + snode; if (node_s >= N) node_s = N - 1;
    const int* Xrow = X + (size_t)node_s * TT;
    auto teff = [&](int t) { return dir ? (TT - 1 - t) : t; };

    { // stage x(0) into buffer 0
        int idx0 = Xrow[teff(0)];
        *(ushort4*)(smem + sb)        = *(const ushort4*)(ehi + (size_t)idx0 * 128 + sk);
        *(ushort4*)(smem + 8192 + sb) = *(const ushort4*)(elo + (size_t)idx0 * 128 + sk);
    }
    int idxA = Xrow[teff(1)];    // index for x(1), prefetched

    float hprev[4] = {0.f, 0.f, 0.f, 0.f};
    const int jd = j & ~1;       // even col of the (j, j^1) pair

    for (int t = 0; t < TT; t++) {
        __syncthreads();   // buf[cur] (x_t + h_t) fully written

        char* pA = smem + (t & 1) * 16384;        // current buffer
        char* pN = smem + ((t + 1) & 1) * 16384;  // next buffer

        // issue next-step staging loads (latency hidden under MFMA)
        ushort4 uhi, ulo;
        if (t < TT - 1) {
            uhi = *(const ushort4*)(ehi + (size_t)idxA * 128 + sk);
            ulo = *(const ushort4*)(elo + (size_t)idxA * 128 + sk);
            if (t < TT - 2) idxA = Xrow[teff(t + 2)];
        }

        f32x4 aR  = (f32x4){0.f, 0.f, 0.f, 0.f};
        f32x4 aZ  = (f32x4){0.f, 0.f, 0.f, 0.f};
        f32x4 aNX = (f32x4){0.f, 0.f, 0.f, 0.f};
        f32x4 aNH = (f32x4){0.f, 0.f, 0.f, 0.f};
        #pragma unroll
        for (int kc = 0; kc < 8; kc++) {
            int ao = (abase + kc * 64) ^ amask;
            short8 ah = *(const short8*)(pA + ao);
            short8 al = *(const short8*)(pA + 8192 + ao);
            f32x4& an = (kc < 4) ? aNX : aNH;
            aR = __builtin_amdgcn_mfma_f32_16x16x32_bf16(ah, bh[0][kc], aR, 0, 0, 0);
            aZ = __builtin_amdgcn_mfma_f32_16x16x32_bf16(ah, bh[1][kc], aZ, 0, 0, 0);
            an = __builtin_amdgcn_mfma_f32_16x16x32_bf16(ah, bh[2][kc], an, 0, 0, 0);
            aR = __builtin_amdgcn_mfma_f32_16x16x32_bf16(al, bh[0][kc], aR, 0, 0, 0);
            aZ = __builtin_amdgcn_mfma_f32_16x16x32_bf16(al, bh[1][kc], aZ, 0, 0, 0);
            an = __builtin_amdgcn_mfma_f32_16x16x32_bf16(al, bh[2][kc], an, 0, 0, 0);
        }

        // gates + h carry; h(t+1) goes to NEXT buffer (packed b32 writes)
        #pragma unroll
        for (int rr = 0; rr < 4; rr++) {
            int nl = l4 * 4 + rr;      // local node (C/D row map)
            float r = 1.f / (1.f + __expf(-(aR[rr] + bR)));
            float z = 1.f / (1.f + __expf(-(aZ[rr] + bZ)));
            float p = aNX[rr] + bXN + r * (aNH[rr] + bHN);
            float n = 1.f - 2.f / (__expf(2.f * p) + 1.f);   // tanh, overflow-safe
            float h = (1.f - z) * n + z * hprev[rr];
            hprev[rr] = h;
            unsigned short hh = f2bf(h);
            unsigned short ll = f2bf(h - bf2f(hh));
            unsigned pk = (unsigned)hh | ((unsigned)ll << 16);
            unsigned pp = __shfl_xor(pk, 1);
            if ((l15 & 1) == 0) {      // even lane writes the (j, j+1) pair
                unsigned hiw = (pk & 0xFFFFu) | (pp << 16);
                unsigned low = (pk >> 16) | (pp & 0xFFFF0000u);
                int hb = (nl * 512 + 256 + 2 * jd) ^ ((nl & 7) << 4);
                *(unsigned*)(pN + hb) = hiw;
                *(unsigned*)(pN + 8192 + hb) = low;
            }
            int node = base + nl;
            if (node < N) {
                q_out[((size_t)t * N + node) * 256 + dir * 128 + j] = h;
                if (t == TT - 1)
                    qn_out[(size_t)node * 256 + dir * 128 + j] = h;
            }
        }
        // write staged x(t+1) into next buffer
        if (t < TT - 1) {
            *(ushort4*)(pN + sb)        = uhi;
            *(ushort4*)(pN + 8192 + sb) = ulo;
        }
    }
}

// ---------- GAT: h = g @ Wg.T via bf16 MFMA 3-pass ----------
__global__ __launch_bounds__(256)
void gat_matmul(const float* __restrict__ G,
                const unsigned short* __restrict__ Wghi, const unsigned short* __restrict__ Wglo,
                float* __restrict__ Hout, int N) {
    const int base = blockIdx.x * 32;
    const int tid  = threadIdx.x;
    const int lane = tid & 63;
    const int w    = tid >> 6;      // wave 0..3
    const int l15  = lane & 15;
    const int l4   = lane >> 4;

    __shared__ __align__(16) char smem[32768];   // hi @0, lo @16384

    // staging: snode = tid>>3 (0..31), sk = (tid&7)*32 (k per thread: 32)
    const int snode = tid >> 3;
    const int sk    = (tid & 7) * 32;
    const int smask = (snode & 7) << 4;
    int node_s = base + snode; if (node_s >= N) node_s = N - 1;
    const float* gr = G + (size_t)node_s * 256 + sk;
    #pragma unroll
    for (int c = 0; c < 4; c++) {
        float4 v0 = *(const float4*)(gr + c * 8);
        float4 v1 = *(const float4*)(gr + c * 8 + 4);
        unsigned short h0 = f2bf(v0.x), h1 = f2bf(v0.y), h2 = f2bf(v0.z), h3 = f2bf(v0.w);
        unsigned short h4 = f2bf(v1.x), h5 = f2bf(v1.y), h6 = f2bf(v1.z), h7 = f2bf(v1.w);
        uint4 hi = {(unsigned)h0 | ((unsigned)h1 << 16), (unsigned)h2 | ((unsigned)h3 << 16),
                    (unsigned)h4 | ((unsigned)h5 << 16), (unsigned)h6 | ((unsigned)h7 << 16)};
        uint4 lo = {(unsigned)f2bf(v0.x - bf2f(h0)) | ((unsigned)f2bf(v0.y - bf2f(h1)) << 16),
                    (unsigned)f2bf(v0.z - bf2f(h2)) | ((unsigned)f2bf(v0.w - bf2f(h3)) << 16),
                    (unsigned)f2bf(v1.x - bf2f(h4)) | ((unsigned)f2bf(v1.y - bf2f(h5)) << 16),
                    (unsigned)f2bf(v1.z - bf2f(h6)) | ((unsigned)f2bf(v1.w - bf2f(h7)) << 16)};
        int addr = (snode * 512 + (sk + c * 8) * 2) ^ smask;
        *(uint4*)(smem + addr) = hi;
        *(uint4*)(smem + 16384 + addr) = lo;
    }
    __syncthreads();

    // A-frag bases for 2 M-tiles
    int aob[2], amask[2];
    #pragma unroll
    for (int mt = 0; mt < 2; mt++) {
        int row = mt * 16 + l15;
        aob[mt]   = row * 512 + l4 * 16;
        amask[mt] = (row & 7) << 4;
    }
    // B-frag bases for 4 col-tiles
    int bb[4];
    #pragma unroll
    for (int th = 0; th < 4; th++)
        bb[th] = (w * 64 + th * 16 + l15) * 256 + l4 * 8;

    f32x4 acc[4][2];
    #pragma unroll
    for (int th = 0; th < 4; th++)
        #pragma unroll
        for (int mt = 0; mt < 2; mt++) acc[th][mt] = (f32x4){0.f, 0.f, 0.f, 0.f};

    #pragma unroll
    for (int kc = 0; kc < 8; kc++) {
        short8 ah[2], al[2];
        #pragma unroll
        for (int mt = 0; mt < 2; mt++) {
            int ao = (aob[mt] + kc * 64) ^ amask[mt];
            ah[mt] = *(const short8*)(smem + ao);
            al[mt] = *(const short8*)(smem + 16384 + ao);
        }
        #pragma unroll
        for (int th = 0; th < 4; th++) {
            int bo = bb[th] + kc * 32;
            short8 bh = *(const short8*)(Wghi + bo);
            short8 bl = *(const short8*)(Wglo + bo);
            #pragma unroll
            for (int mt = 0; mt < 2; mt++) {
                acc[th][mt] = __builtin_amdgcn_mfma_f32_16x16x32_bf16(ah[mt], bh, acc[th][mt], 0, 0, 0);
                acc[th][mt] = __builtin_amdgcn_mfma_f32_16x16x32_bf16(al[mt], bh, acc[th][mt], 0, 0, 0);
                acc[th][mt] = __builtin_amdgcn_mfma_f32_16x16x32_bf16(ah[mt], bl, acc[th][mt], 0, 0, 0);
            }
        }
    }

    #pragma unroll
    for (int th = 0; th < 4; th++)
        #pragma unroll
        for (int mt = 0; mt < 2; mt++)
            #pragma unroll
            for (int rr = 0; rr < 4; rr++) {
                int node = base + mt * 16 + l4 * 4 + rr;
                int col  = w * 64 + th * 16 + l15;
                if (node < N) Hout[(size_t)node * 256 + col] = acc[th][mt][rr];
            }
}

// ---------- GAT: attention dots + per-node init ----------
__global__ void gat_dots(const float* __restrict__ Hm, const float* __restrict__ att_src,
                         const float* __restrict__ att_dst, float* __restrict__ a_src,
                         float* __restrict__ a_dst, unsigned* __restrict__ mx,
                         float* __restrict__ denom, int N) {
    int node = blockIdx.x * 4 + (threadIdx.x >> 6);
    int lane = threadIdx.x & 63;
    if (node >= N) return;
    const float* hr = Hm + (size_t)node * 256;
    float s1 = 0.f, s2 = 0.f;
    #pragma unroll
    for (int c = 0; c < 4; c++) {
        float h = hr[lane + 64 * c];
        s1 += h * att_src[lane + 64 * c];
        s2 += h * att_dst[lane + 64 * c];
    }
    #pragma unroll
    for (int o = 32; o > 0; o >>= 1) { s1 += __shfl_down(s1, o); s2 += __shfl_down(s2, o); }
    if (lane == 0) {
        a_src[node] = s1; a_dst[node] = s2;
        mx[node] = ENC_NEG_INF; denom[node] = 0.f;
    }
}

__global__ void edge_max(const int* __restrict__ src, const int* __restrict__ dst,
                         const float* __restrict__ a_src, const float* __restrict__ a_dst,
                         unsigned* __restrict__ mx, int E) {
    int i = blockIdx.x * 256 + threadIdx.x;
    if (i >= E) return;
    float v = a_src[src[i]] + a_dst[dst[i]];
    v = v > 0.f ? v : 0.2f * v;
    atomicMax(mx + dst[i], fenc(v));
}

__global__ void edge_exp(const int* __restrict__ src, const int* __restrict__ dst,
                         const float* __restrict__ a_src, const float* __restrict__ a_dst,
                         const unsigned* __restrict__ mx, float* __restrict__ denom,
                         const int* __restrict__ pos_of_edge, float* __restrict__ ex_sorted,
                         int E) {
    int i = blockIdx.x * 256 + threadIdx.x;
    if (i >= E) return;
    float v = a_src[src[i]] + a_dst[dst[i]];
    v = v > 0.f ? v : 0.2f * v;
    float e = __expf(v - fdec(mx[dst[i]]));
    atomicAdd(denom + dst[i], e);
    ex_sorted[pos_of_edge[i]] = e;
}

// ---------- GAT: CSR aggregate — wave per node, float4/lane, x4 unroll ----------
__global__ void gat_aggregate(const float* __restrict__ Hm, const int* __restrict__ off,
                              const int* __restrict__ srcs_sorted,
                              const float* __restrict__ ex_sorted,
                              const float* __restrict__ denom, const float* __restrict__ bias,
                              float* __restrict__ Gout, int N) {
    int n = blockIdx.x * 4 + (threadIdx.x >> 6);
    int lane = threadIdx.x & 63;
    if (n >= N) return;
    int s0 = off[n], s1 = off[n + 1];
    float4 acc = {0.f, 0.f, 0.f, 0.f};
    int e = s0;
    for (; e + 4 <= s1; e += 4) {
        int sA = srcs_sorted[e],     sB = srcs_sorted[e + 1];
        int sC = srcs_sorted[e + 2], sD = srcs_sorted[e + 3];
        float wA = ex_sorted[e],     wB = ex_sorted[e + 1];
        float wC = ex_sorted[e + 2], wD = ex_sorted[e + 3];
        float4 a = *(const float4*)(Hm + (size_t)sA * 256 + lane * 4);
        float4 b = *(const float4*)(Hm + (size_t)sB * 256 + lane * 4);
        float4 c = *(const float4*)(Hm + (size_t)sC * 256 + lane * 4);
        float4 d = *(const float4*)(Hm + (size_t)sD * 256 + lane * 4);
        acc.x += a.x * wA + b.x * wB + c.x * wC + d.x * wD;
        acc.y += a.y * wA + b.y * wB + c.y * wC + d.y * wD;
        acc.z += a.z * wA + b.z * wB + c.z * wC + d.z * wD;
        acc.w += a.w * wA + b.w * wB + c.w * wC + d.w * wD;
    }
    for (; e < s1; e++) {
        int s = srcs_sorted[e];
        float wgt = ex_sorted[e];
        float4 a = *(const float4*)(Hm + (size_t)s * 256 + lane * 4);
        acc.x += a.x * wgt; acc.y += a.y * wgt; acc.z += a.z * wgt; acc.w += a.w * wgt;
    }
    float inv = (s1 > s0) ? 1.f / denom[n] : 0.f;
    float4 b4 = *(const float4*)(bias + lane * 4);
    float4 o = {acc.x * inv + b4.x, acc.y * inv + b4.y,
                acc.z * inv + b4.z, acc.w * inv + b4.w};
    *(float4*)(Gout + (size_t)n * 256 + lane * 4) = o;
}

// ---------- CSR build ----------
__global__ void zero_int(int* p, int n) {
    int i = blockIdx.x * 256 + threadIdx.x;
    if (i < n) p[i] = 0;
}
__global__ void deg_count(const int* __restrict__ dst, int* __restrict__ deg, int E) {
    int i = blockIdx.x * 256 + threadIdx.x;
    if (i < E) atomicAdd(deg + dst[i], 1);
}
__global__ void scan_k(const int* __restrict__ deg, int* __restrict__ off,
                       int* __restrict__ cursor, int n) {
    __shared__ int buf[256];
    __shared__ int carry_s;
    int tid = threadIdx.x;
    if (tid == 0) carry_s = 0;
    __syncthreads();
    for (int base = 0; base < n; base += 256) {
        int v = (base + tid < n) ? deg[base + tid] : 0;
        buf[tid] = v;
        __syncthreads();
        int x = v;
        for (int s = 1; s < 256; s <<= 1) {
            int tv = (tid >= s) ? buf[tid - s] : 0;
            __syncthreads();
            x += tv; buf[tid] = x;
            __syncthreads();
        }
        int carry = carry_s;
        if (base + tid < n) { off[base + tid] = carry + x - v; cursor[base + tid] = carry + x - v; }
        __syncthreads();
        if (tid == 255) carry_s = carry + x;
        __syncthreads();
    }
    if (tid == 0) off[n] = carry_s;
}
__global__ void scatter_k(const int* __restrict__ src, const int* __restrict__ dst,
                          int* __restrict__ cursor, int* __restrict__ srcs_sorted,
                          int* __restrict__ pos_of_edge, int E) {
    int i = blockIdx.x * 256 + threadIdx.x;
    if (i >= E) return;
    int p = atomicAdd(cursor + dst[i], 1);
    srcs_sorted[p] = src[i];
    pos_of_edge[i] = p;
}

// ---------- launch ----------
extern "C" void kernel_launch(void* const* d_in, const int* in_sizes, int n_in,
                              void* d_out, int out_size, void* d_ws, size_t ws_size,
                              hipStream_t stream) {
    const int N = in_sizes[0] / TT;
    const int E = in_sizes[1] / 2;
    const int EMBN = in_sizes[2];          // V * 128

    const int* X         = (const int*)d_in[0];
    const int* ei        = (const int*)d_in[1];
    const int* srcp      = ei;
    const int* dstp      = ei + E;
    const float* emb     = (const float*)d_in[2];
    const float* Wih_f   = (const float*)d_in[3];
    const float* Whh_f   = (const float*)d_in[4];
    const float* bih_f   = (const float*)d_in[5];
    const float* bhh_f   = (const float*)d_in[6];
    const float* Wih_b   = (const float*)d_in[7];
    const float* Whh_b   = (const float*)d_in[8];
    const float* bih_b   = (const float*)d_in[9];
    const float* bhh_b   = (const float*)d_in[10];
    const float* Wg      = (const float*)d_in[11];
    const float* att_src = (const float*)d_in[12];
    const float* att_dst = (const float*)d_in[13];
    const float* bg      = (const float*)d_in[14];

    float* out     = (float*)d_out;
    float* g_final = out;
    float* qn      = out + (size_t)N * 256;
    float* q       = out + (size_t)2 * N * 256;

    // ws layout
    float* w = (float*)d_ws;
    unsigned short* Whi_f = (unsigned short*)w; w += 49152;  // 384*256 ushort
    unsigned short* Whi_b = (unsigned short*)w; w += 49152;
    unsigned short* Wghi  = (unsigned short*)w; w += 32768;  // 256*256 ushort
    unsigned short* Wglo  = (unsigned short*)w; w += 32768;
    unsigned short* ehi   = (unsigned short*)w; w += (EMBN + 1) / 2;
    unsigned short* elo   = (unsigned short*)w; w += (EMBN + 1) / 2;
    float* bufA  = w; w += (size_t)N * 256;
    float* bufB  = w; w += (size_t)N * 256;
    float* Hbuf  = w; w += (size_t)N * 256;
    float* a_src = w; w += N;
    float* a_dst = w; w += N;
    float* denom = w; w += N;
    unsigned* mx = (unsigned*)w; w += N;
    float* ex_sorted = w; w += E;
    int* iw = (int*)w;
    int* deg         = iw; iw += N;
    int* cursor      = iw; iw += N;
    int* off         = iw; iw += N + 1;
    int* srcs_sorted = iw; iw += E;
    int* pos_of_edge = iw; iw += E;

    // 1. weight + emb plane prep
    prep_w<<<384, 256, 0, stream>>>(Wih_f, Whh_f, Wih_b, Whh_b, Wg,
                                    Whi_f, Whi_b, Wghi, Wglo);
    prep_emb<<<(EMBN + 255) / 256, 256, 0, stream>>>(emb, ehi, elo, EMBN);
    // 2. fused biGRU (2-pass), writes q and q_n
    dim3 ggrid((N + NB - 1) / NB, 2);
    gru_kernel<<<ggrid, 512, 0, stream>>>(X, ehi, elo, Whi_f, Whi_b,
                                          bih_f, bhh_f, bih_b, bhh_b, q, qn, N);
    // 3. CSR build (once, reused by all 4 layers)
    zero_int<<<(N + 255) / 256, 256, 0, stream>>>(deg, N);
    deg_count<<<(E + 255) / 256, 256, 0, stream>>>(dstp, deg, E);
    scan_k<<<1, 256, 0, stream>>>(deg, off, cursor, N);
    scatter_k<<<(E + 255) / 256, 256, 0, stream>>>(srcp, dstp, cursor, srcs_sorted,
                                                   pos_of_edge, E);
    // 4. 4 GAT layers (shared weights)
    const float* gin = qn;
    float* gouts[4] = {bufA, bufB, bufA, g_final};
    for (int l = 0; l < 4; l++) {
        gat_matmul<<<(N + 31) / 32, 256, 0, stream>>>(gin, Wghi, Wglo, Hbuf, N);
        gat_dots<<<(N + 3) / 4, 256, 0, stream>>>(Hbuf, att_src, att_dst, a_src, a_dst,
                                                  mx, denom, N);
        edge_max<<<(E + 255) / 256, 256, 0, stream>>>(srcp, dstp, a_src, a_dst, mx, E);
        edge_exp<<<(E + 255) / 256, 256, 0, stream>>>(srcp, dstp, a_src, a_dst, mx, denom,
                                                      pos_of_edge, ex_sorted, E);
        gat_aggregate<<<(N + 3) / 4, 256, 0, stream>>>(Hbuf, off, srcs_sorted, ex_sorted,
                                                       denom, bg, gouts[l], N);
        gin = gouts[l];
    }
}